// Round 1
// baseline (997.151 us; speedup 1.0000x reference)
//
#include <hip/hip_runtime.h>
#include <hip/hip_bf16.h>

#define D_MODEL 1024
#define D_INNER 2048
#define NEXP 8
#define TOPK 2

#define BM 64
#define BN 64
#define BK 32
#define LDP 40   // padded LDS K-stride (ushorts): 80B rows, 16B-aligned

typedef float f32x4 __attribute__((ext_vector_type(4)));
typedef short bf16x8 __attribute__((ext_vector_type(8)));

__device__ __forceinline__ unsigned short f2b(float f) {
    union { float f; unsigned int u; } v; v.f = f;
    unsigned int u = v.u;
    return (unsigned short)((u + 0x7fffu + ((u >> 16) & 1u)) >> 16);
}

// ---------------- router: 1 wave per token ----------------
__global__ __launch_bounds__(64) void router_kernel(
    const float* __restrict__ x, const float* __restrict__ rw,
    const float* __restrict__ rb, int* __restrict__ top_i,
    float* __restrict__ top_w, int T)
{
    int t = blockIdx.x;
    if (t >= T) return;
    int l = threadIdx.x;
    float xv[16];
#pragma unroll
    for (int i = 0; i < 16; i++) xv[i] = x[(size_t)t * D_MODEL + l + 64 * i];
    float logit[NEXP];
#pragma unroll
    for (int e = 0; e < NEXP; e++) {
        float acc = 0.f;
#pragma unroll
        for (int i = 0; i < 16; i++) acc += xv[i] * rw[e * D_MODEL + l + 64 * i];
#pragma unroll
        for (int s = 32; s > 0; s >>= 1) acc += __shfl_xor(acc, s, 64);
        logit[e] = acc + rb[e];
    }
    if (l == 0) {
        int i0 = 0; float m0 = logit[0];
#pragma unroll
        for (int e = 1; e < NEXP; e++) if (logit[e] > m0) { m0 = logit[e]; i0 = e; }
        int i1 = -1; float m1 = -3.0e38f;
#pragma unroll
        for (int e = 0; e < NEXP; e++) {
            if (e == i0) continue;
            if (logit[e] > m1) { m1 = logit[e]; i1 = e; }
        }
        // renormalized top-2 softmax
        float w0 = 1.f / (1.f + expf(m1 - m0));
        top_i[t * 2 + 0] = i0; top_i[t * 2 + 1] = i1;
        top_w[t * 2 + 0] = w0; top_w[t * 2 + 1] = 1.f - w0;
    }
}

// ---------------- deterministic bucket build: 1 block ----------------
__global__ __launch_bounds__(256) void bucket_kernel(
    const int* __restrict__ top_i, const float* __restrict__ top_w,
    int* __restrict__ expert_off, int* __restrict__ tok_of_slot,
    float* __restrict__ w_of_slot, int T)
{
    __shared__ int cnt[256][NEXP];
    __shared__ int pre[256][NEXP];
    __shared__ int tot[NEXP];
    __shared__ int off[NEXP + 1];
    int tid = threadIdx.x;
    int per = (T + 255) / 256;
    int t0 = tid * per;
    for (int e = 0; e < NEXP; e++) cnt[tid][e] = 0;
    for (int t = t0; t < t0 + per && t < T; t++)
        for (int k = 0; k < TOPK; k++) cnt[tid][top_i[t * 2 + k]]++;
    __syncthreads();
    if (tid < NEXP) {
        int run = 0;
        for (int i = 0; i < 256; i++) { pre[i][tid] = run; run += cnt[i][tid]; }
        tot[tid] = run;
    }
    __syncthreads();
    if (tid == 0) {
        off[0] = 0;
        for (int e = 0; e < NEXP; e++) off[e + 1] = off[e] + tot[e];
        for (int e = 0; e <= NEXP; e++) expert_off[e] = off[e];
    }
    __syncthreads();
    int lc[NEXP];
#pragma unroll
    for (int e = 0; e < NEXP; e++) lc[e] = 0;
    for (int t = t0; t < t0 + per && t < T; t++) {
        for (int k = 0; k < TOPK; k++) {
            int e = top_i[t * 2 + k];
            int slot = off[e] + pre[tid][e] + lc[e]++;
            tok_of_slot[slot] = t;
            w_of_slot[slot] = top_w[t * 2 + k];
        }
    }
}

// ---------------- gate+up GEMM + swiglu -> H (bf16) ----------------
__global__ __launch_bounds__(256) void moe_gate_up(
    const float* __restrict__ x, const float* __restrict__ gate_w,
    const float* __restrict__ up_w, const int* __restrict__ expert_off,
    const int* __restrict__ tok_of_slot, unsigned short* __restrict__ H,
    int ntiles)
{
    __shared__ unsigned short As[BM][LDP];
    __shared__ unsigned short Bg[BN][LDP];
    __shared__ unsigned short Bu[BN][LDP];
    __shared__ int toks[BM];

    int e = blockIdx.x / ntiles;
    int tile = blockIdx.x % ntiles;
    int row0 = expert_off[e] + tile * BM;
    int rowEnd = expert_off[e + 1];
    if (row0 >= rowEnd) return;
    int Mloc = min(BM, rowEnd - row0);
    int f0 = blockIdx.y * BN;

    int tid = threadIdx.x;
    if (tid < BM) toks[tid] = (tid < Mloc) ? tok_of_slot[row0 + tid] : -1;
    __syncthreads();

    int wave = tid >> 6, lane = tid & 63;
    int wm = wave >> 1, wn = wave & 1;
    int lrow = lane & 15, kgrp = lane >> 4;

    f32x4 accg[2][2], accu[2][2];
#pragma unroll
    for (int i = 0; i < 2; i++)
#pragma unroll
        for (int j = 0; j < 2; j++) {
            accg[i][j] = (f32x4){0.f, 0.f, 0.f, 0.f};
            accu[i][j] = (f32x4){0.f, 0.f, 0.f, 0.f};
        }

    const float* gbase = gate_w + (size_t)e * D_MODEL * D_INNER;
    const float* ubase = up_w + (size_t)e * D_MODEL * D_INNER;

    for (int k0 = 0; k0 < D_MODEL; k0 += BK) {
        // stage A (gathered x rows), fp32 -> bf16
#pragma unroll
        for (int it = 0; it < 2; it++) {
            int i = tid + it * 256;
            int r = i >> 3, cg = i & 7;
            int tok = toks[r];
            float4 v = make_float4(0.f, 0.f, 0.f, 0.f);
            if (tok >= 0) v = *(const float4*)&x[(size_t)tok * D_MODEL + k0 + cg * 4];
            union { unsigned short s[4]; uint2 u; } p;
            p.s[0] = f2b(v.x); p.s[1] = f2b(v.y); p.s[2] = f2b(v.z); p.s[3] = f2b(v.w);
            *(uint2*)&As[r][cg * 4] = p.u;
        }
        // stage B gate & up ([K][N] global -> transposed [N][K] LDS)
#pragma unroll
        for (int it = 0; it < 2; it++) {
            int i = tid + it * 256;
            int k = i >> 4, n = (i & 15) * 4;
            float4 vg = *(const float4*)&gbase[(size_t)(k0 + k) * D_INNER + f0 + n];
            float4 vu = *(const float4*)&ubase[(size_t)(k0 + k) * D_INNER + f0 + n];
            Bg[n + 0][k] = f2b(vg.x); Bg[n + 1][k] = f2b(vg.y);
            Bg[n + 2][k] = f2b(vg.z); Bg[n + 3][k] = f2b(vg.w);
            Bu[n + 0][k] = f2b(vu.x); Bu[n + 1][k] = f2b(vu.y);
            Bu[n + 2][k] = f2b(vu.z); Bu[n + 3][k] = f2b(vu.w);
        }
        __syncthreads();

        bf16x8 a[2], bg[2], bu[2];
#pragma unroll
        for (int fm = 0; fm < 2; fm++)
            a[fm] = *(const bf16x8*)&As[wm * 32 + fm * 16 + lrow][kgrp * 8];
#pragma unroll
        for (int fn = 0; fn < 2; fn++) {
            bg[fn] = *(const bf16x8*)&Bg[wn * 32 + fn * 16 + lrow][kgrp * 8];
            bu[fn] = *(const bf16x8*)&Bu[wn * 32 + fn * 16 + lrow][kgrp * 8];
        }
#pragma unroll
        for (int fm = 0; fm < 2; fm++)
#pragma unroll
            for (int fn = 0; fn < 2; fn++) {
                accg[fm][fn] = __builtin_amdgcn_mfma_f32_16x16x32_bf16(a[fm], bg[fn], accg[fm][fn], 0, 0, 0);
                accu[fm][fn] = __builtin_amdgcn_mfma_f32_16x16x32_bf16(a[fm], bu[fn], accu[fm][fn], 0, 0, 0);
            }
        __syncthreads();
    }

    // epilogue: h = silu(g)*u -> H bf16
#pragma unroll
    for (int fm = 0; fm < 2; fm++) {
#pragma unroll
        for (int fn = 0; fn < 2; fn++) {
#pragma unroll
            for (int r = 0; r < 4; r++) {
                int m = wm * 32 + fm * 16 + kgrp * 4 + r;
                if (m < Mloc) {
                    int n = wn * 32 + fn * 16 + lrow;
                    float g = accg[fm][fn][r], u = accu[fm][fn][r];
                    float h = g / (1.f + __expf(-g)) * u;
                    H[(size_t)(row0 + m) * D_INNER + f0 + n] = f2b(h);
                }
            }
        }
    }
}

// ---------------- down GEMM + weighted scatter ----------------
__global__ __launch_bounds__(256) void moe_down(
    const unsigned short* __restrict__ H, const float* __restrict__ down_w,
    const int* __restrict__ expert_off, const int* __restrict__ tok_of_slot,
    const float* __restrict__ w_of_slot, float* __restrict__ out, int ntiles)
{
    __shared__ unsigned short As[BM][LDP];
    __shared__ unsigned short Bs[BN][LDP];
    __shared__ int toks[BM];
    __shared__ float wts[BM];

    int e = blockIdx.x / ntiles;
    int tile = blockIdx.x % ntiles;
    int row0 = expert_off[e] + tile * BM;
    int rowEnd = expert_off[e + 1];
    if (row0 >= rowEnd) return;
    int Mloc = min(BM, rowEnd - row0);
    int d0 = blockIdx.y * BN;

    int tid = threadIdx.x;
    if (tid < BM) {
        toks[tid] = (tid < Mloc) ? tok_of_slot[row0 + tid] : -1;
        wts[tid] = (tid < Mloc) ? w_of_slot[row0 + tid] : 0.f;
    }
    __syncthreads();

    int wave = tid >> 6, lane = tid & 63;
    int wm = wave >> 1, wn = wave & 1;
    int lrow = lane & 15, kgrp = lane >> 4;

    f32x4 acc[2][2];
#pragma unroll
    for (int i = 0; i < 2; i++)
#pragma unroll
        for (int j = 0; j < 2; j++) acc[i][j] = (f32x4){0.f, 0.f, 0.f, 0.f};

    const float* dbase = down_w + (size_t)e * D_INNER * D_MODEL;

    for (int k0 = 0; k0 < D_INNER; k0 += BK) {
        // stage A from H (already bf16)
#pragma unroll
        for (int it = 0; it < 2; it++) {
            int i = tid + it * 256;
            int r = i >> 3, cg = i & 7;
            uint2 v = make_uint2(0u, 0u);
            if (r < Mloc) v = *(const uint2*)&H[(size_t)(row0 + r) * D_INNER + k0 + cg * 4];
            *(uint2*)&As[r][cg * 4] = v;
        }
        // stage B down_w ([K][N] -> transposed)
#pragma unroll
        for (int it = 0; it < 2; it++) {
            int i = tid + it * 256;
            int k = i >> 4, n = (i & 15) * 4;
            float4 v = *(const float4*)&dbase[(size_t)(k0 + k) * D_MODEL + d0 + n];
            Bs[n + 0][k] = f2b(v.x); Bs[n + 1][k] = f2b(v.y);
            Bs[n + 2][k] = f2b(v.z); Bs[n + 3][k] = f2b(v.w);
        }
        __syncthreads();

        bf16x8 a[2], b[2];
#pragma unroll
        for (int fm = 0; fm < 2; fm++)
            a[fm] = *(const bf16x8*)&As[wm * 32 + fm * 16 + lrow][kgrp * 8];
#pragma unroll
        for (int fn = 0; fn < 2; fn++)
            b[fn] = *(const bf16x8*)&Bs[wn * 32 + fn * 16 + lrow][kgrp * 8];
#pragma unroll
        for (int fm = 0; fm < 2; fm++)
#pragma unroll
            for (int fn = 0; fn < 2; fn++)
                acc[fm][fn] = __builtin_amdgcn_mfma_f32_16x16x32_bf16(a[fm], b[fn], acc[fm][fn], 0, 0, 0);
        __syncthreads();
    }

#pragma unroll
    for (int fm = 0; fm < 2; fm++) {
#pragma unroll
        for (int fn = 0; fn < 2; fn++) {
#pragma unroll
            for (int r = 0; r < 4; r++) {
                int m = wm * 32 + fm * 16 + kgrp * 4 + r;
                if (m < Mloc) {
                    int n = wn * 32 + fn * 16 + lrow;
                    atomicAdd(&out[(size_t)toks[m] * D_MODEL + d0 + n],
                              wts[m] * acc[fm][fn][r]);
                }
            }
        }
    }
}

extern "C" void kernel_launch(void* const* d_in, const int* in_sizes, int n_in,
                              void* d_out, int out_size, void* d_ws, size_t ws_size,
                              hipStream_t stream) {
    const float* x  = (const float*)d_in[0];
    const float* rw = (const float*)d_in[1];
    const float* rb = (const float*)d_in[2];
    const float* gw = (const float*)d_in[3];
    const float* uw = (const float*)d_in[4];
    const float* dw = (const float*)d_in[5];
    float* out = (float*)d_out;

    int T = in_sizes[0] / D_MODEL;          // 4096
    int S2 = 2 * T;                          // slots

    char* ws = (char*)d_ws;
    int*   top_i = (int*)ws;                               // 2T ints
    float* top_w = (float*)(ws + (size_t)S2 * 4);          // 2T floats
    int*   eoff  = (int*)(ws + (size_t)S2 * 8);            // 16 ints (9 used)
    int*   tos   = (int*)(ws + (size_t)S2 * 8 + 64);       // 2T ints
    float* wos   = (float*)(ws + (size_t)S2 * 8 + 64 + (size_t)S2 * 4);
    unsigned short* H = (unsigned short*)(ws + (size_t)S2 * 8 + 64 + (size_t)S2 * 8); // 2T*F bf16

    hipMemsetAsync(d_out, 0, (size_t)out_size * sizeof(float), stream);

    router_kernel<<<T, 64, 0, stream>>>(x, rw, rb, top_i, top_w, T);
    bucket_kernel<<<1, 256, 0, stream>>>(top_i, top_w, eoff, tos, wos, T);

    int ntiles = (T + BM - 1) / BM;          // 64 (worst case: all tokens on one expert)
    dim3 g1(NEXP * ntiles, D_INNER / BN);
    moe_gate_up<<<g1, 256, 0, stream>>>(x, gw, uw, eoff, tos, H, ntiles);
    dim3 g2(NEXP * ntiles, D_MODEL / BN);
    moe_down<<<g2, 256, 0, stream>>>(H, dw, eoff, tos, wos, out, ntiles);
}

// Round 2
// 469.008 us; speedup vs baseline: 2.1261x; 2.1261x over previous
//
#include <hip/hip_runtime.h>
#include <hip/hip_bf16.h>
#include <stdint.h>

#define D_MODEL 1024
#define D_INNER 2048
#define NEXP 8
#define TOPK 2
#define BM 128

typedef float f32x4 __attribute__((ext_vector_type(4)));
typedef short bf16x8 __attribute__((ext_vector_type(8)));

__device__ __forceinline__ unsigned short f2b(float f) {
    union { float f; uint32_t u; } v; v.f = f;
    uint32_t u = v.u;
    return (unsigned short)((u + 0x7fffu + ((u >> 16) & 1u)) >> 16);
}

// async global->LDS, 16B per lane; dest = wave-uniform base + lane*16
__device__ __forceinline__ void gl_lds16(const void* g, void* l) {
    __builtin_amdgcn_global_load_lds((const __attribute__((address_space(1))) void*)g,
                                     (__attribute__((address_space(3))) void*)l, 16, 0, 0);
}

// ---------------- cast x: fp32 -> bf16 ----------------
__global__ __launch_bounds__(256) void cast_x_kernel(
    const float* __restrict__ in, unsigned short* __restrict__ out, int n8)
{
    int i = blockIdx.x * 256 + threadIdx.x;
    if (i >= n8) return;
    const float4* p = (const float4*)(in + (size_t)i * 8);
    float4 a = p[0], b = p[1];
    unsigned short o[8] = {f2b(a.x), f2b(a.y), f2b(a.z), f2b(a.w),
                           f2b(b.x), f2b(b.y), f2b(b.z), f2b(b.w)};
    *(uint4*)(out + (size_t)i * 8) = *(uint4*)o;
}

// ------------- cast+transpose weights: [E][K][N] fp32 -> [E][N][K] bf16 -------------
__global__ __launch_bounds__(256) void tcast_kernel(
    const float* __restrict__ in, unsigned short* __restrict__ out, int K, int N)
{
    __shared__ unsigned short S[64][68];
    int e = blockIdx.z;
    int n0 = blockIdx.x * 64, k0 = blockIdx.y * 64;
    const float* ib = in + (size_t)e * K * N;
    unsigned short* ob = out + (size_t)e * N * K;
    int tid = threadIdx.x;
    int kk = tid >> 4, nn4 = (tid & 15) * 4;
#pragma unroll
    for (int j = 0; j < 4; j++) {
        int k = kk + 16 * j;
        float4 v = *(const float4*)&ib[(size_t)(k0 + k) * N + n0 + nn4];
        ushort4 s; s.x = f2b(v.x); s.y = f2b(v.y); s.z = f2b(v.z); s.w = f2b(v.w);
        *(ushort4*)&S[k][nn4] = s;
    }
    __syncthreads();
    int nn = tid >> 4, kk4 = (tid & 15) * 4;
#pragma unroll
    for (int j = 0; j < 4; j++) {
        int n = nn + 16 * j;
        ushort4 s;
        s.x = S[kk4 + 0][n]; s.y = S[kk4 + 1][n];
        s.z = S[kk4 + 2][n]; s.w = S[kk4 + 3][n];
        *(ushort4*)&ob[(size_t)(n0 + n) * K + k0 + kk4] = s;
    }
}

// ---------------- router: 1 wave per token ----------------
__global__ __launch_bounds__(64) void router_kernel(
    const float* __restrict__ x, const float* __restrict__ rw,
    const float* __restrict__ rb, int* __restrict__ top_i,
    float* __restrict__ top_w, int T)
{
    int t = blockIdx.x;
    if (t >= T) return;
    int l = threadIdx.x;
    float xv[16];
#pragma unroll
    for (int i = 0; i < 16; i++) xv[i] = x[(size_t)t * D_MODEL + l + 64 * i];
    float logit[NEXP];
#pragma unroll
    for (int e = 0; e < NEXP; e++) {
        float acc = 0.f;
#pragma unroll
        for (int i = 0; i < 16; i++) acc += xv[i] * rw[e * D_MODEL + l + 64 * i];
#pragma unroll
        for (int s = 32; s > 0; s >>= 1) acc += __shfl_xor(acc, s, 64);
        logit[e] = acc + rb[e];
    }
    if (l == 0) {
        int i0 = 0; float m0 = logit[0];
#pragma unroll
        for (int e = 1; e < NEXP; e++) if (logit[e] > m0) { m0 = logit[e]; i0 = e; }
        int i1 = -1; float m1 = -3.0e38f;
#pragma unroll
        for (int e = 0; e < NEXP; e++) {
            if (e == i0) continue;
            if (logit[e] > m1) { m1 = logit[e]; i1 = e; }
        }
        float w0 = 1.f / (1.f + expf(m1 - m0));
        top_i[t * 2 + 0] = i0; top_i[t * 2 + 1] = i1;
        top_w[t * 2 + 0] = w0; top_w[t * 2 + 1] = 1.f - w0;
    }
}

// ---------------- deterministic bucket build: 1 block ----------------
__global__ __launch_bounds__(256) void bucket_kernel(
    const int* __restrict__ top_i, const float* __restrict__ top_w,
    int* __restrict__ expert_off, int* __restrict__ tok_of_slot,
    float* __restrict__ w_of_slot, int T)
{
    __shared__ int cnt[256][NEXP];
    __shared__ int pre[256][NEXP];
    __shared__ int tot[NEXP];
    __shared__ int off[NEXP + 1];
    int tid = threadIdx.x;
    int per = (T + 255) / 256;
    int t0 = tid * per;
    for (int e = 0; e < NEXP; e++) cnt[tid][e] = 0;
    for (int t = t0; t < t0 + per && t < T; t++)
        for (int k = 0; k < TOPK; k++) cnt[tid][top_i[t * 2 + k]]++;
    __syncthreads();
    if (tid < NEXP) {
        int run = 0;
        for (int i = 0; i < 256; i++) { pre[i][tid] = run; run += cnt[i][tid]; }
        tot[tid] = run;
    }
    __syncthreads();
    if (tid == 0) {
        off[0] = 0;
        for (int e = 0; e < NEXP; e++) off[e + 1] = off[e] + tot[e];
        for (int e = 0; e <= NEXP; e++) expert_off[e] = off[e];
    }
    __syncthreads();
    int lc[NEXP];
#pragma unroll
    for (int e = 0; e < NEXP; e++) lc[e] = 0;
    for (int t = t0; t < t0 + per && t < T; t++) {
        for (int k = 0; k < TOPK; k++) {
            int e = top_i[t * 2 + k];
            int slot = off[e] + pre[tid][e] + lc[e]++;
            tok_of_slot[slot] = t;
            w_of_slot[slot] = top_w[t * 2 + k];
        }
    }
}

// ---------------- gate+up GEMM + swiglu -> H (bf16) ----------------
// A: gathered x rows [128 x 64] bf16, Bg/Bu: [64 x 64] bf16 (weights pre-transposed [N][K]).
// All staging via global_load_lds; LDS linear; 16B-chunk XOR swizzle (c ^= row&7) applied
// on the per-lane SOURCE address and again on the ds_read address (involution).
__global__ __launch_bounds__(256, 2) void moe_gate_up(
    const unsigned short* __restrict__ xb, const unsigned short* __restrict__ wgT,
    const unsigned short* __restrict__ wuT, const int* __restrict__ expert_off,
    const int* __restrict__ tok_of_slot, unsigned short* __restrict__ H, int ntiles)
{
    __shared__ unsigned short As[BM * 64];
    __shared__ unsigned short Bg[64 * 64];
    __shared__ unsigned short Bu[64 * 64];

    int e = blockIdx.x / ntiles, tile = blockIdx.x % ntiles;
    int row0 = expert_off[e] + tile * BM;
    int rowEnd = expert_off[e + 1];
    if (row0 >= rowEnd) return;
    int Mloc = min(BM, rowEnd - row0);
    int f0 = blockIdx.y * 64;

    int tid = threadIdx.x, wv = tid >> 6, lane = tid & 63;
    int l3 = lane >> 3, c3 = lane & 7;

    // per-thread staging source pointers (element units)
    const unsigned short* srcA[4];
#pragma unroll
    for (int j = 0; j < 4; j++) {
        int r = wv * 32 + j * 8 + l3;
        int slot = row0 + ((r < Mloc) ? r : 0);
        int tok = tok_of_slot[slot];
        srcA[j] = xb + (size_t)tok * D_MODEL + 8 * (c3 ^ (r & 7));
    }
    const unsigned short* srcG[2]; const unsigned short* srcU[2];
#pragma unroll
    for (int j = 0; j < 2; j++) {
        int r = wv * 16 + j * 8 + l3;
        size_t off = (size_t)e * D_MODEL * D_INNER + (size_t)(f0 + r) * D_MODEL + 8 * (c3 ^ (r & 7));
        srcG[j] = wgT + off; srcU[j] = wuT + off;
    }

    int wm = wv >> 1, wn = wv & 1;
    int lrow = lane & 15, kgrp = lane >> 4;
    int swz = lrow & 7;

    f32x4 accg[4][2], accu[4][2];
#pragma unroll
    for (int i = 0; i < 4; i++)
#pragma unroll
        for (int j = 0; j < 2; j++) {
            accg[i][j] = (f32x4){0.f, 0.f, 0.f, 0.f};
            accu[i][j] = (f32x4){0.f, 0.f, 0.f, 0.f};
        }

    int arow[4], brow[2];
#pragma unroll
    for (int fm = 0; fm < 4; fm++) arow[fm] = (wm * 64 + fm * 16 + lrow) * 64;
#pragma unroll
    for (int fn = 0; fn < 2; fn++) brow[fn] = (wn * 32 + fn * 16 + lrow) * 64;

    for (int k0 = 0; k0 < D_MODEL; k0 += 64) {
#pragma unroll
        for (int j = 0; j < 4; j++)
            gl_lds16(srcA[j] + k0, As + (wv * 256 + j * 64) * 8);
#pragma unroll
        for (int j = 0; j < 2; j++) {
            gl_lds16(srcG[j] + k0, Bg + (wv * 128 + j * 64) * 8);
            gl_lds16(srcU[j] + k0, Bu + (wv * 128 + j * 64) * 8);
        }
        __syncthreads();
#pragma unroll
        for (int ks = 0; ks < 2; ks++) {
            int co = 8 * ((4 * ks + kgrp) ^ swz);
            bf16x8 a[4], bg[2], bu[2];
#pragma unroll
            for (int fm = 0; fm < 4; fm++) a[fm] = *(const bf16x8*)&As[arow[fm] + co];
#pragma unroll
            for (int fn = 0; fn < 2; fn++) {
                bg[fn] = *(const bf16x8*)&Bg[brow[fn] + co];
                bu[fn] = *(const bf16x8*)&Bu[brow[fn] + co];
            }
#pragma unroll
            for (int fm = 0; fm < 4; fm++)
#pragma unroll
                for (int fn = 0; fn < 2; fn++) {
                    accg[fm][fn] = __builtin_amdgcn_mfma_f32_16x16x32_bf16(a[fm], bg[fn], accg[fm][fn], 0, 0, 0);
                    accu[fm][fn] = __builtin_amdgcn_mfma_f32_16x16x32_bf16(a[fm], bu[fn], accu[fm][fn], 0, 0, 0);
                }
        }
        __syncthreads();
    }

#pragma unroll
    for (int fm = 0; fm < 4; fm++)
#pragma unroll
        for (int fn = 0; fn < 2; fn++)
#pragma unroll
            for (int r = 0; r < 4; r++) {
                int m = wm * 64 + fm * 16 + kgrp * 4 + r;
                if (m < Mloc) {
                    int n = wn * 32 + fn * 16 + lrow;
                    float g = accg[fm][fn][r], u = accu[fm][fn][r];
                    float h = g / (1.f + __expf(-g)) * u;
                    H[(size_t)(row0 + m) * D_INNER + f0 + n] = f2b(h);
                }
            }
}

// ---------------- down GEMM + weighted scatter ----------------
__global__ __launch_bounds__(256, 2) void moe_down(
    const unsigned short* __restrict__ H, const unsigned short* __restrict__ wdT,
    const int* __restrict__ expert_off, const int* __restrict__ tok_of_slot,
    const float* __restrict__ w_of_slot, float* __restrict__ out, int ntiles, int S2)
{
    __shared__ unsigned short As[BM * 64];
    __shared__ unsigned short Bs[BM * 64];
    __shared__ int toks[BM];
    __shared__ float wts[BM];

    int e = blockIdx.x / ntiles, tile = blockIdx.x % ntiles;
    int row0 = expert_off[e] + tile * BM;
    int rowEnd = expert_off[e + 1];
    if (row0 >= rowEnd) return;
    int Mloc = min(BM, rowEnd - row0);
    int d0 = blockIdx.y * BM;

    int tid = threadIdx.x, wv = tid >> 6, lane = tid & 63;
    int l3 = lane >> 3, c3 = lane & 7;
    if (tid < BM) {
        bool v = tid < Mloc;
        toks[tid] = v ? tok_of_slot[row0 + tid] : 0;
        wts[tid] = v ? w_of_slot[row0 + tid] : 0.f;
    }

    const unsigned short* srcA[4]; const unsigned short* srcB[4];
#pragma unroll
    for (int j = 0; j < 4; j++) {
        int r = wv * 32 + j * 8 + l3;
        int slot = min(row0 + r, S2 - 1);
        srcA[j] = H + (size_t)slot * D_INNER + 8 * (c3 ^ (r & 7));
        srcB[j] = wdT + (size_t)e * D_INNER * D_MODEL + (size_t)(d0 + r) * D_INNER + 8 * (c3 ^ (r & 7));
    }

    int wm = wv >> 1, wn = wv & 1;
    int lrow = lane & 15, kgrp = lane >> 4;
    int swz = lrow & 7;

    f32x4 acc[4][4];
#pragma unroll
    for (int i = 0; i < 4; i++)
#pragma unroll
        for (int j = 0; j < 4; j++) acc[i][j] = (f32x4){0.f, 0.f, 0.f, 0.f};

    int arow[4], brow[4];
#pragma unroll
    for (int fm = 0; fm < 4; fm++) arow[fm] = (wm * 64 + fm * 16 + lrow) * 64;
#pragma unroll
    for (int fn = 0; fn < 4; fn++) brow[fn] = (wn * 64 + fn * 16 + lrow) * 64;

    for (int k0 = 0; k0 < D_INNER; k0 += 64) {
#pragma unroll
        for (int j = 0; j < 4; j++) {
            gl_lds16(srcA[j] + k0, As + (wv * 256 + j * 64) * 8);
            gl_lds16(srcB[j] + k0, Bs + (wv * 256 + j * 64) * 8);
        }
        __syncthreads();
#pragma unroll
        for (int ks = 0; ks < 2; ks++) {
            int co = 8 * ((4 * ks + kgrp) ^ swz);
            bf16x8 a[4], b[4];
#pragma unroll
            for (int fm = 0; fm < 4; fm++) a[fm] = *(const bf16x8*)&As[arow[fm] + co];
#pragma unroll
            for (int fn = 0; fn < 4; fn++) b[fn] = *(const bf16x8*)&Bs[brow[fn] + co];
#pragma unroll
            for (int fm = 0; fm < 4; fm++)
#pragma unroll
                for (int fn = 0; fn < 4; fn++)
                    acc[fm][fn] = __builtin_amdgcn_mfma_f32_16x16x32_bf16(a[fm], b[fn], acc[fm][fn], 0, 0, 0);
        }
        __syncthreads();
    }

#pragma unroll
    for (int fm = 0; fm < 4; fm++)
#pragma unroll
        for (int fn = 0; fn < 4; fn++)
#pragma unroll
            for (int r = 0; r < 4; r++) {
                int m = wm * 64 + fm * 16 + kgrp * 4 + r;
                if (m < Mloc) {
                    int n = wn * 64 + fn * 16 + lrow;
                    atomicAdd(&out[(size_t)toks[m] * D_MODEL + d0 + n], wts[m] * acc[fm][fn][r]);
                }
            }
}

extern "C" void kernel_launch(void* const* d_in, const int* in_sizes, int n_in,
                              void* d_out, int out_size, void* d_ws, size_t ws_size,
                              hipStream_t stream) {
    const float* x  = (const float*)d_in[0];
    const float* rw = (const float*)d_in[1];
    const float* rb = (const float*)d_in[2];
    const float* gw = (const float*)d_in[3];
    const float* uw = (const float*)d_in[4];
    const float* dw = (const float*)d_in[5];
    float* out = (float*)d_out;

    int T = in_sizes[0] / D_MODEL;   // 4096
    int S2 = 2 * T;                   // 8192 slots

    // workspace carve-up
    char* ws = (char*)d_ws;
    size_t cur = 0;
    auto take = [&](size_t bytes) { char* p = ws + cur; cur = (cur + bytes + 255) & ~(size_t)255; return p; };
    int*   top_i = (int*)take((size_t)S2 * 4);
    float* top_w = (float*)take((size_t)S2 * 4);
    int*   eoff  = (int*)take(64);
    int*   tos   = (int*)take((size_t)S2 * 4);
    float* wos   = (float*)take((size_t)S2 * 4);
    unsigned short* xb  = (unsigned short*)take((size_t)T * D_MODEL * 2);
    unsigned short* wgT = (unsigned short*)take((size_t)NEXP * D_MODEL * D_INNER * 2);
    unsigned short* wuT = (unsigned short*)take((size_t)NEXP * D_MODEL * D_INNER * 2);
    unsigned short* wdT = (unsigned short*)take((size_t)NEXP * D_MODEL * D_INNER * 2);
    unsigned short* H   = (unsigned short*)take((size_t)S2 * D_INNER * 2);

    hipMemsetAsync(d_out, 0, (size_t)out_size * sizeof(float), stream);

    int n8 = T * D_MODEL / 8;
    cast_x_kernel<<<(n8 + 255) / 256, 256, 0, stream>>>(x, xb, n8);
    tcast_kernel<<<dim3(D_INNER / 64, D_MODEL / 64, NEXP), 256, 0, stream>>>(gw, wgT, D_MODEL, D_INNER);
    tcast_kernel<<<dim3(D_INNER / 64, D_MODEL / 64, NEXP), 256, 0, stream>>>(uw, wuT, D_MODEL, D_INNER);
    tcast_kernel<<<dim3(D_MODEL / 64, D_INNER / 64, NEXP), 256, 0, stream>>>(dw, wdT, D_INNER, D_MODEL);

    router_kernel<<<T, 64, 0, stream>>>(x, rw, rb, top_i, top_w, T);
    bucket_kernel<<<1, 256, 0, stream>>>(top_i, top_w, eoff, tos, wos, T);

    int ntiles = (S2 + BM - 1) / BM;  // worst case: all slots on one expert
    dim3 g1(NEXP * ntiles, D_INNER / 64);
    moe_gate_up<<<g1, 256, 0, stream>>>(xb, wgT, wuT, eoff, tos, H, ntiles);
    dim3 g2(NEXP * ntiles, D_MODEL / BM);
    moe_down<<<g2, 256, 0, stream>>>(H, wdT, eoff, tos, wos, out, ntiles, S2);
}

// Round 3
// 303.581 us; speedup vs baseline: 3.2846x; 1.5449x over previous
//
#include <hip/hip_runtime.h>
#include <hip/hip_bf16.h>
#include <stdint.h>

#define D_MODEL 1024
#define D_INNER 2048
#define NEXP 8
#define TOPK 2
#define BM 128
#define MAXT 72   // max M-tiles: floor(8192/128) + (NEXP-1) = 71, padded

typedef float f32x4 __attribute__((ext_vector_type(4)));
typedef short bf16x8 __attribute__((ext_vector_type(8)));

__device__ __forceinline__ unsigned short f2b(float f) {
    union { float f; uint32_t u; } v; v.f = f;
    uint32_t u = v.u;
    return (unsigned short)((u + 0x7fffu + ((u >> 16) & 1u)) >> 16);
}

__device__ __forceinline__ void gl_lds16(const void* g, void* l) {
    __builtin_amdgcn_global_load_lds((const __attribute__((address_space(1))) void*)g,
                                     (__attribute__((address_space(3))) void*)l, 16, 0, 0);
}

// ---------------- cast x: fp32 -> bf16 ----------------
__global__ __launch_bounds__(256) void cast_x_kernel(
    const float* __restrict__ in, unsigned short* __restrict__ out, int n8)
{
    int i = blockIdx.x * 256 + threadIdx.x;
    if (i >= n8) return;
    const float4* p = (const float4*)(in + (size_t)i * 8);
    float4 a = p[0], b = p[1];
    unsigned short o[8] = {f2b(a.x), f2b(a.y), f2b(a.z), f2b(a.w),
                           f2b(b.x), f2b(b.y), f2b(b.z), f2b(b.w)};
    *(uint4*)(out + (size_t)i * 8) = *(uint4*)o;
}

// ------------- cast+transpose weights: [E][K][N] fp32 -> [E][N][K] bf16 -------------
__global__ __launch_bounds__(256) void tcast_kernel(
    const float* __restrict__ in, unsigned short* __restrict__ out, int K, int N)
{
    __shared__ unsigned short S[64][68];
    int e = blockIdx.z;
    int n0 = blockIdx.x * 64, k0 = blockIdx.y * 64;
    const float* ib = in + (size_t)e * K * N;
    unsigned short* ob = out + (size_t)e * N * K;
    int tid = threadIdx.x;
    int kk = tid >> 4, nn4 = (tid & 15) * 4;
#pragma unroll
    for (int j = 0; j < 4; j++) {
        int k = kk + 16 * j;
        float4 v = *(const float4*)&ib[(size_t)(k0 + k) * N + n0 + nn4];
        ushort4 s; s.x = f2b(v.x); s.y = f2b(v.y); s.z = f2b(v.z); s.w = f2b(v.w);
        *(ushort4*)&S[k][nn4] = s;
    }
    __syncthreads();
    int nn = tid >> 4, kk4 = (tid & 15) * 4;
#pragma unroll
    for (int j = 0; j < 4; j++) {
        int n = nn + 16 * j;
        ushort4 s;
        s.x = S[kk4 + 0][n]; s.y = S[kk4 + 1][n];
        s.z = S[kk4 + 2][n]; s.w = S[kk4 + 3][n];
        *(ushort4*)&ob[(size_t)(n0 + n) * K + k0 + kk4] = s;
    }
}

// ---------------- router: 1 wave per token ----------------
__global__ __launch_bounds__(64) void router_kernel(
    const float* __restrict__ x, const float* __restrict__ rw,
    const float* __restrict__ rb, int* __restrict__ top_i,
    float* __restrict__ top_w, int T)
{
    int t = blockIdx.x;
    if (t >= T) return;
    int l = threadIdx.x;
    float xv[16];
#pragma unroll
    for (int i = 0; i < 16; i++) xv[i] = x[(size_t)t * D_MODEL + l + 64 * i];
    float logit[NEXP];
#pragma unroll
    for (int e = 0; e < NEXP; e++) {
        float acc = 0.f;
#pragma unroll
        for (int i = 0; i < 16; i++) acc += xv[i] * rw[e * D_MODEL + l + 64 * i];
#pragma unroll
        for (int s = 32; s > 0; s >>= 1) acc += __shfl_xor(acc, s, 64);
        logit[e] = acc + rb[e];
    }
    if (l == 0) {
        int i0 = 0; float m0 = logit[0];
#pragma unroll
        for (int e = 1; e < NEXP; e++) if (logit[e] > m0) { m0 = logit[e]; i0 = e; }
        int i1 = -1; float m1 = -3.0e38f;
#pragma unroll
        for (int e = 0; e < NEXP; e++) {
            if (e == i0) continue;
            if (logit[e] > m1) { m1 = logit[e]; i1 = e; }
        }
        float w0 = 1.f / (1.f + expf(m1 - m0));
        top_i[t * 2 + 0] = i0; top_i[t * 2 + 1] = i1;
        top_w[t * 2 + 0] = w0; top_w[t * 2 + 1] = 1.f - w0;
    }
}

// ---------------- bucket build + compact tile worklist: 1 block ----------------
// meta layout (ints): [0..8] expert offsets; [16..16+MAXT) packed tiles (e<<16|row0, -1 pad)
__global__ __launch_bounds__(256) void bucket_kernel(
    const int* __restrict__ top_i, const float* __restrict__ top_w,
    int* __restrict__ meta, int* __restrict__ tok_of_slot,
    float* __restrict__ w_of_slot, int T)
{
    __shared__ int cnt[256][NEXP];
    __shared__ int pre[256][NEXP];
    __shared__ int tot[NEXP];
    __shared__ int off[NEXP + 1];
    int tid = threadIdx.x;
    int per = (T + 255) / 256;
    int t0 = tid * per;
    for (int e = 0; e < NEXP; e++) cnt[tid][e] = 0;
    for (int t = t0; t < t0 + per && t < T; t++)
        for (int k = 0; k < TOPK; k++) cnt[tid][top_i[t * 2 + k]]++;
    __syncthreads();
    if (tid < NEXP) {
        int run = 0;
        for (int i = 0; i < 256; i++) { pre[i][tid] = run; run += cnt[i][tid]; }
        tot[tid] = run;
    }
    __syncthreads();
    if (tid == 0) {
        off[0] = 0;
        for (int e = 0; e < NEXP; e++) off[e + 1] = off[e] + tot[e];
        for (int e = 0; e <= NEXP; e++) meta[e] = off[e];
        int nt = 0;
        for (int e = 0; e < NEXP; e++)
            for (int r = off[e]; r < off[e + 1]; r += BM)
                meta[16 + nt++] = (e << 16) | r;
        for (; nt < MAXT; nt++) meta[16 + nt] = -1;
    }
    __syncthreads();
    int lc[NEXP];
#pragma unroll
    for (int e = 0; e < NEXP; e++) lc[e] = 0;
    for (int t = t0; t < t0 + per && t < T; t++) {
        for (int k = 0; k < TOPK; k++) {
            int e = top_i[t * 2 + k];
            int slot = off[e] + pre[tid][e] + lc[e]++;
            tok_of_slot[slot] = t;
            w_of_slot[slot] = top_w[t * 2 + k];
        }
    }
}

// ---------------- gate+up GEMM + swiglu -> H, 2-phase pipelined ----------------
// grid.x = MAXT*32 (1-D). lin%8 selects XCD -> f-group, so each XCD's L2 holds an
// 8MB weight slice; tile index = lin>>5 equivalent via decomposition below.
__global__ __launch_bounds__(256, 2) void moe_gate_up(
    const unsigned short* __restrict__ xb, const unsigned short* __restrict__ wgT,
    const unsigned short* __restrict__ wuT, const int* __restrict__ meta,
    const int* __restrict__ tok_of_slot, unsigned short* __restrict__ H)
{
    __shared__ unsigned short As[2][BM * 64];
    __shared__ unsigned short Bg[2][64 * 64];
    __shared__ unsigned short Bu[2][64 * 64];

    int lin = blockIdx.x;
    int xcd = lin & 7, idx = lin >> 3;
    int tix = idx >> 2;
    int f0 = (xcd * 4 + (idx & 3)) * 64;
    int packed = meta[16 + tix];
    if (packed < 0) return;
    int e = packed >> 16, row0 = packed & 0xffff;
    int Mloc = min(BM, meta[e + 1] - row0);

    int tid = threadIdx.x, wv = tid >> 6, lane = tid & 63;
    int l3 = lane >> 3, c3 = lane & 7;

    const unsigned short* srcA[4];
#pragma unroll
    for (int j = 0; j < 4; j++) {
        int r = wv * 32 + j * 8 + l3;
        int slot = row0 + ((r < Mloc) ? r : 0);
        int tok = tok_of_slot[slot];
        srcA[j] = xb + (size_t)tok * D_MODEL + 8 * (c3 ^ (r & 7));
    }
    const unsigned short* srcG[2]; const unsigned short* srcU[2];
#pragma unroll
    for (int j = 0; j < 2; j++) {
        int r = wv * 16 + j * 8 + l3;
        size_t off = (size_t)e * D_MODEL * D_INNER + (size_t)(f0 + r) * D_MODEL + 8 * (c3 ^ (r & 7));
        srcG[j] = wgT + off; srcU[j] = wuT + off;
    }

    int wm = wv >> 1, wn = wv & 1;
    int lrow = lane & 15, kgrp = lane >> 4;
    int swz = lrow & 7;

    f32x4 accg[4][2], accu[4][2];
#pragma unroll
    for (int i = 0; i < 4; i++)
#pragma unroll
        for (int j = 0; j < 2; j++) {
            accg[i][j] = (f32x4){0.f, 0.f, 0.f, 0.f};
            accu[i][j] = (f32x4){0.f, 0.f, 0.f, 0.f};
        }

    int arow[4], brow[2];
#pragma unroll
    for (int fm = 0; fm < 4; fm++) arow[fm] = (wm * 64 + fm * 16 + lrow) * 64;
#pragma unroll
    for (int fn = 0; fn < 2; fn++) brow[fn] = (wn * 32 + fn * 16 + lrow) * 64;

    // prologue: stage k-tile 0 into buf 0
#pragma unroll
    for (int j = 0; j < 4; j++) gl_lds16(srcA[j], As[0] + (wv * 256 + j * 64) * 8);
#pragma unroll
    for (int j = 0; j < 2; j++) {
        gl_lds16(srcG[j], Bg[0] + (wv * 128 + j * 64) * 8);
        gl_lds16(srcU[j], Bu[0] + (wv * 128 + j * 64) * 8);
    }
    __syncthreads();

    int cur = 0;
    for (int k0 = 0; k0 < D_MODEL; k0 += 64, cur ^= 1) {
        if (k0 + 64 < D_MODEL) {   // stage next k-tile into buf cur^1 (overlaps compute)
            int nxt = cur ^ 1, kn = k0 + 64;
#pragma unroll
            for (int j = 0; j < 4; j++) gl_lds16(srcA[j] + kn, As[nxt] + (wv * 256 + j * 64) * 8);
#pragma unroll
            for (int j = 0; j < 2; j++) {
                gl_lds16(srcG[j] + kn, Bg[nxt] + (wv * 128 + j * 64) * 8);
                gl_lds16(srcU[j] + kn, Bu[nxt] + (wv * 128 + j * 64) * 8);
            }
        }
        const unsigned short* Ac = As[cur];
        const unsigned short* Gc = Bg[cur];
        const unsigned short* Uc = Bu[cur];
#pragma unroll
        for (int ks = 0; ks < 2; ks++) {
            int co = 8 * ((4 * ks + kgrp) ^ swz);
            bf16x8 a[4], bg[2], bu[2];
#pragma unroll
            for (int fm = 0; fm < 4; fm++) a[fm] = *(const bf16x8*)&Ac[arow[fm] + co];
#pragma unroll
            for (int fn = 0; fn < 2; fn++) {
                bg[fn] = *(const bf16x8*)&Gc[brow[fn] + co];
                bu[fn] = *(const bf16x8*)&Uc[brow[fn] + co];
            }
#pragma unroll
            for (int fm = 0; fm < 4; fm++)
#pragma unroll
                for (int fn = 0; fn < 2; fn++) {
                    accg[fm][fn] = __builtin_amdgcn_mfma_f32_16x16x32_bf16(a[fm], bg[fn], accg[fm][fn], 0, 0, 0);
                    accu[fm][fn] = __builtin_amdgcn_mfma_f32_16x16x32_bf16(a[fm], bu[fn], accu[fm][fn], 0, 0, 0);
                }
        }
        __syncthreads();   // drains vmcnt (staged tile ready) + protects buf reuse
    }

#pragma unroll
    for (int fm = 0; fm < 4; fm++)
#pragma unroll
        for (int fn = 0; fn < 2; fn++)
#pragma unroll
            for (int r = 0; r < 4; r++) {
                int m = wm * 64 + fm * 16 + kgrp * 4 + r;
                if (m < Mloc) {
                    int n = wn * 32 + fn * 16 + lrow;
                    float g = accg[fm][fn][r], u = accu[fm][fn][r];
                    float h = g / (1.f + __expf(-g)) * u;
                    H[(size_t)(row0 + m) * D_INNER + f0 + n] = f2b(h);
                }
            }
}

// ---------------- down GEMM + weighted scatter, 2-phase pipelined ----------------
// grid.x = MAXT*8; lin%8 = XCD = d-strip -> per-XCD down_w slice = 4MB (L2-resident)
__global__ __launch_bounds__(256, 2) void moe_down(
    const unsigned short* __restrict__ H, const unsigned short* __restrict__ wdT,
    const int* __restrict__ meta, const int* __restrict__ tok_of_slot,
    const float* __restrict__ w_of_slot, float* __restrict__ out, int S2)
{
    __shared__ unsigned short As[2][BM * 64];
    __shared__ unsigned short Bs[2][BM * 64];
    __shared__ int toks[BM];
    __shared__ float wts[BM];

    int lin = blockIdx.x;
    int d0 = (lin & 7) * BM;
    int tix = lin >> 3;
    int packed = meta[16 + tix];
    if (packed < 0) return;
    int e = packed >> 16, row0 = packed & 0xffff;
    int Mloc = min(BM, meta[e + 1] - row0);

    int tid = threadIdx.x, wv = tid >> 6, lane = tid & 63;
    int l3 = lane >> 3, c3 = lane & 7;
    if (tid < BM) {
        bool v = tid < Mloc;
        toks[tid] = v ? tok_of_slot[row0 + tid] : 0;
        wts[tid] = v ? w_of_slot[row0 + tid] : 0.f;
    }

    const unsigned short* srcA[4]; const unsigned short* srcB[4];
#pragma unroll
    for (int j = 0; j < 4; j++) {
        int r = wv * 32 + j * 8 + l3;
        int slot = min(row0 + r, S2 - 1);
        srcA[j] = H + (size_t)slot * D_INNER + 8 * (c3 ^ (r & 7));
        srcB[j] = wdT + (size_t)e * D_INNER * D_MODEL + (size_t)(d0 + r) * D_INNER + 8 * (c3 ^ (r & 7));
    }

    int wm = wv >> 1, wn = wv & 1;
    int lrow = lane & 15, kgrp = lane >> 4;
    int swz = lrow & 7;

    f32x4 acc[4][4];
#pragma unroll
    for (int i = 0; i < 4; i++)
#pragma unroll
        for (int j = 0; j < 4; j++) acc[i][j] = (f32x4){0.f, 0.f, 0.f, 0.f};

    int arow[4], brow[4];
#pragma unroll
    for (int fm = 0; fm < 4; fm++) arow[fm] = (wm * 64 + fm * 16 + lrow) * 64;
#pragma unroll
    for (int fn = 0; fn < 4; fn++) brow[fn] = (wn * 64 + fn * 16 + lrow) * 64;

#pragma unroll
    for (int j = 0; j < 4; j++) {
        gl_lds16(srcA[j], As[0] + (wv * 256 + j * 64) * 8);
        gl_lds16(srcB[j], Bs[0] + (wv * 256 + j * 64) * 8);
    }
    __syncthreads();

    int cur = 0;
    for (int k0 = 0; k0 < D_INNER; k0 += 64, cur ^= 1) {
        if (k0 + 64 < D_INNER) {
            int nxt = cur ^ 1, kn = k0 + 64;
#pragma unroll
            for (int j = 0; j < 4; j++) {
                gl_lds16(srcA[j] + kn, As[nxt] + (wv * 256 + j * 64) * 8);
                gl_lds16(srcB[j] + kn, Bs[nxt] + (wv * 256 + j * 64) * 8);
            }
        }
        const unsigned short* Ac = As[cur];
        const unsigned short* Bc = Bs[cur];
#pragma unroll
        for (int ks = 0; ks < 2; ks++) {
            int co = 8 * ((4 * ks + kgrp) ^ swz);
            bf16x8 a[4], b[4];
#pragma unroll
            for (int fm = 0; fm < 4; fm++) a[fm] = *(const bf16x8*)&Ac[arow[fm] + co];
#pragma unroll
            for (int fn = 0; fn < 4; fn++) b[fn] = *(const bf16x8*)&Bc[brow[fn] + co];
#pragma unroll
            for (int fm = 0; fm < 4; fm++)
#pragma unroll
                for (int fn = 0; fn < 4; fn++)
                    acc[fm][fn] = __builtin_amdgcn_mfma_f32_16x16x32_bf16(a[fm], b[fn], acc[fm][fn], 0, 0, 0);
        }
        __syncthreads();
    }

#pragma unroll
    for (int fm = 0; fm < 4; fm++)
#pragma unroll
        for (int fn = 0; fn < 4; fn++)
#pragma unroll
            for (int r = 0; r < 4; r++) {
                int m = wm * 64 + fm * 16 + kgrp * 4 + r;
                if (m < Mloc) {
                    int n = wn * 64 + fn * 16 + lrow;
                    atomicAdd(&out[(size_t)toks[m] * D_MODEL + d0 + n], wts[m] * acc[fm][fn][r]);
                }
            }
}

extern "C" void kernel_launch(void* const* d_in, const int* in_sizes, int n_in,
                              void* d_out, int out_size, void* d_ws, size_t ws_size,
                              hipStream_t stream) {
    const float* x  = (const float*)d_in[0];
    const float* rw = (const float*)d_in[1];
    const float* rb = (const float*)d_in[2];
    const float* gw = (const float*)d_in[3];
    const float* uw = (const float*)d_in[4];
    const float* dw = (const float*)d_in[5];
    float* out = (float*)d_out;

    int T = in_sizes[0] / D_MODEL;   // 4096
    int S2 = 2 * T;                   // 8192 slots

    char* ws = (char*)d_ws;
    size_t cur = 0;
    auto take = [&](size_t bytes) { char* p = ws + cur; cur = (cur + bytes + 255) & ~(size_t)255; return p; };
    int*   top_i = (int*)take((size_t)S2 * 4);
    float* top_w = (float*)take((size_t)S2 * 4);
    int*   meta  = (int*)take(1024);
    int*   tos   = (int*)take((size_t)S2 * 4);
    float* wos   = (float*)take((size_t)S2 * 4);
    unsigned short* xb  = (unsigned short*)take((size_t)T * D_MODEL * 2);
    unsigned short* wgT = (unsigned short*)take((size_t)NEXP * D_MODEL * D_INNER * 2);
    unsigned short* wuT = (unsigned short*)take((size_t)NEXP * D_MODEL * D_INNER * 2);
    unsigned short* wdT = (unsigned short*)take((size_t)NEXP * D_MODEL * D_INNER * 2);
    unsigned short* H   = (unsigned short*)take((size_t)S2 * D_INNER * 2);

    hipMemsetAsync(d_out, 0, (size_t)out_size * sizeof(float), stream);

    int n8 = T * D_MODEL / 8;
    cast_x_kernel<<<(n8 + 255) / 256, 256, 0, stream>>>(x, xb, n8);
    tcast_kernel<<<dim3(D_INNER / 64, D_MODEL / 64, NEXP), 256, 0, stream>>>(gw, wgT, D_MODEL, D_INNER);
    tcast_kernel<<<dim3(D_INNER / 64, D_MODEL / 64, NEXP), 256, 0, stream>>>(uw, wuT, D_MODEL, D_INNER);
    tcast_kernel<<<dim3(D_MODEL / 64, D_INNER / 64, NEXP), 256, 0, stream>>>(dw, wdT, D_INNER, D_MODEL);

    router_kernel<<<T, 64, 0, stream>>>(x, rw, rb, top_i, top_w, T);
    bucket_kernel<<<1, 256, 0, stream>>>(top_i, top_w, meta, tos, wos, T);

    moe_gate_up<<<MAXT * 32, 256, 0, stream>>>(xb, wgT, wuT, meta, tos, H);
    moe_down<<<MAXT * 8, 256, 0, stream>>>(H, wdT, meta, tos, wos, out, S2);
}

// Round 4
// 293.815 us; speedup vs baseline: 3.3938x; 1.0332x over previous
//
#include <hip/hip_runtime.h>
#include <hip/hip_bf16.h>
#include <stdint.h>

#define D_MODEL 1024
#define D_INNER 2048
#define NEXP 8
#define TOPK 2
#define BM 128
#define MAXT 72   // max M-tiles: floor(8192/128) + (NEXP-1) = 71, padded

typedef float f32x4 __attribute__((ext_vector_type(4)));
typedef short bf16x8 __attribute__((ext_vector_type(8)));

#define MEMFENCE asm volatile("" ::: "memory")

__device__ __forceinline__ unsigned short f2b(float f) {
    union { float f; uint32_t u; } v; v.f = f;
    uint32_t u = v.u;
    return (unsigned short)((u + 0x7fffu + ((u >> 16) & 1u)) >> 16);
}

__device__ __forceinline__ void gl_lds16(const void* g, void* l) {
    __builtin_amdgcn_global_load_lds((const __attribute__((address_space(1))) void*)g,
                                     (__attribute__((address_space(3))) void*)l, 16, 0, 0);
}

// ---------------- cast x: fp32 -> bf16 ----------------
__global__ __launch_bounds__(256) void cast_x_kernel(
    const float* __restrict__ in, unsigned short* __restrict__ out, int n8)
{
    int i = blockIdx.x * 256 + threadIdx.x;
    if (i >= n8) return;
    const float4* p = (const float4*)(in + (size_t)i * 8);
    float4 a = p[0], b = p[1];
    unsigned short o[8] = {f2b(a.x), f2b(a.y), f2b(a.z), f2b(a.w),
                           f2b(b.x), f2b(b.y), f2b(b.z), f2b(b.w)};
    *(uint4*)(out + (size_t)i * 8) = *(uint4*)o;
}

// ------------- cast+transpose weights: [E][K][N] fp32 -> [E][N][K] bf16 -------------
__global__ __launch_bounds__(256) void tcast_kernel(
    const float* __restrict__ in, unsigned short* __restrict__ out, int K, int N)
{
    __shared__ unsigned short S[64][68];
    int e = blockIdx.z;
    int n0 = blockIdx.x * 64, k0 = blockIdx.y * 64;
    const float* ib = in + (size_t)e * K * N;
    unsigned short* ob = out + (size_t)e * N * K;
    int tid = threadIdx.x;
    int kk = tid >> 4, nn4 = (tid & 15) * 4;
#pragma unroll
    for (int j = 0; j < 4; j++) {
        int k = kk + 16 * j;
        float4 v = *(const float4*)&ib[(size_t)(k0 + k) * N + n0 + nn4];
        ushort4 s; s.x = f2b(v.x); s.y = f2b(v.y); s.z = f2b(v.z); s.w = f2b(v.w);
        *(ushort4*)&S[k][nn4] = s;
    }
    __syncthreads();
    int nn = tid >> 4, kk4 = (tid & 15) * 4;
#pragma unroll
    for (int j = 0; j < 4; j++) {
        int n = nn + 16 * j;
        ushort4 s;
        s.x = S[kk4 + 0][n]; s.y = S[kk4 + 1][n];
        s.z = S[kk4 + 2][n]; s.w = S[kk4 + 3][n];
        *(ushort4*)&ob[(size_t)(n0 + n) * K + k0 + kk4] = s;
    }
}

// ---------------- router: 1 wave per token ----------------
__global__ __launch_bounds__(64) void router_kernel(
    const float* __restrict__ x, const float* __restrict__ rw,
    const float* __restrict__ rb, int* __restrict__ top_i,
    float* __restrict__ top_w, int T)
{
    int t = blockIdx.x;
    if (t >= T) return;
    int l = threadIdx.x;
    float xv[16];
#pragma unroll
    for (int i = 0; i < 16; i++) xv[i] = x[(size_t)t * D_MODEL + l + 64 * i];
    float logit[NEXP];
#pragma unroll
    for (int e = 0; e < NEXP; e++) {
        float acc = 0.f;
#pragma unroll
        for (int i = 0; i < 16; i++) acc += xv[i] * rw[e * D_MODEL + l + 64 * i];
#pragma unroll
        for (int s = 32; s > 0; s >>= 1) acc += __shfl_xor(acc, s, 64);
        logit[e] = acc + rb[e];
    }
    if (l == 0) {
        int i0 = 0; float m0 = logit[0];
#pragma unroll
        for (int e = 1; e < NEXP; e++) if (logit[e] > m0) { m0 = logit[e]; i0 = e; }
        int i1 = -1; float m1 = -3.0e38f;
#pragma unroll
        for (int e = 0; e < NEXP; e++) {
            if (e == i0) continue;
            if (logit[e] > m1) { m1 = logit[e]; i1 = e; }
        }
        float w0 = 1.f / (1.f + expf(m1 - m0));
        top_i[t * 2 + 0] = i0; top_i[t * 2 + 1] = i1;
        top_w[t * 2 + 0] = w0; top_w[t * 2 + 1] = 1.f - w0;
    }
}

// ---------------- bucket build + compact tile worklist: 1 block ----------------
// meta layout (ints): [0..8] expert offsets; [16..16+MAXT) packed tiles (e<<16|row0, -1 pad)
__global__ __launch_bounds__(256) void bucket_kernel(
    const int* __restrict__ top_i, const float* __restrict__ top_w,
    int* __restrict__ meta, int* __restrict__ tok_of_slot,
    float* __restrict__ w_of_slot, int T)
{
    __shared__ int cnt[256][NEXP];
    __shared__ int pre[256][NEXP];
    __shared__ int tot[NEXP];
    __shared__ int off[NEXP + 1];
    int tid = threadIdx.x;
    int per = (T + 255) / 256;
    int t0 = tid * per;
    for (int e = 0; e < NEXP; e++) cnt[tid][e] = 0;
    for (int t = t0; t < t0 + per && t < T; t++)
        for (int k = 0; k < TOPK; k++) cnt[tid][top_i[t * 2 + k]]++;
    __syncthreads();
    if (tid < NEXP) {
        int run = 0;
        for (int i = 0; i < 256; i++) { pre[i][tid] = run; run += cnt[i][tid]; }
        tot[tid] = run;
    }
    __syncthreads();
    if (tid == 0) {
        off[0] = 0;
        for (int e = 0; e < NEXP; e++) off[e + 1] = off[e] + tot[e];
        for (int e = 0; e <= NEXP; e++) meta[e] = off[e];
        int nt = 0;
        for (int e = 0; e < NEXP; e++)
            for (int r = off[e]; r < off[e + 1]; r += BM)
                meta[16 + nt++] = (e << 16) | r;
        for (; nt < MAXT; nt++) meta[16 + nt] = -1;
    }
    __syncthreads();
    int lc[NEXP];
#pragma unroll
    for (int e = 0; e < NEXP; e++) lc[e] = 0;
    for (int t = t0; t < t0 + per && t < T; t++) {
        for (int k = 0; k < TOPK; k++) {
            int e = top_i[t * 2 + k];
            int slot = off[e] + pre[tid][e] + lc[e]++;
            tok_of_slot[slot] = t;
            w_of_slot[slot] = top_w[t * 2 + k];
        }
    }
}

// ---------------- gate+up GEMM + swiglu -> H, counted-vmcnt pipeline ----------------
__global__ __launch_bounds__(256, 2) void moe_gate_up(
    const unsigned short* __restrict__ xb, const unsigned short* __restrict__ wgT,
    const unsigned short* __restrict__ wuT, const int* __restrict__ meta,
    const int* __restrict__ tok_of_slot, unsigned short* __restrict__ H)
{
    __shared__ unsigned short As[2][BM * 64];
    __shared__ unsigned short Bg[2][64 * 64];
    __shared__ unsigned short Bu[2][64 * 64];

    int lin = blockIdx.x;
    int xcd = lin & 7, idx = lin >> 3;
    int tix = idx >> 2;
    int f0 = (xcd * 4 + (idx & 3)) * 64;
    int packed = meta[16 + tix];
    if (packed < 0) return;
    int e = packed >> 16, row0 = packed & 0xffff;
    int Mloc = min(BM, meta[e + 1] - row0);

    int tid = threadIdx.x, wv = tid >> 6, lane = tid & 63;
    int l3 = lane >> 3, c3 = lane & 7;

    const unsigned short* srcA[4];
#pragma unroll
    for (int j = 0; j < 4; j++) {
        int r = wv * 32 + j * 8 + l3;
        int slot = row0 + ((r < Mloc) ? r : 0);
        int tok = tok_of_slot[slot];
        srcA[j] = xb + (size_t)tok * D_MODEL + 8 * (c3 ^ (r & 7));
    }
    const unsigned short* srcG[2]; const unsigned short* srcU[2];
#pragma unroll
    for (int j = 0; j < 2; j++) {
        int r = wv * 16 + j * 8 + l3;
        size_t off = (size_t)e * D_MODEL * D_INNER + (size_t)(f0 + r) * D_MODEL + 8 * (c3 ^ (r & 7));
        srcG[j] = wgT + off; srcU[j] = wuT + off;
    }

    int wm = wv >> 1, wn = wv & 1;
    int lrow = lane & 15, kgrp = lane >> 4;
    int swz = lrow & 7;

    f32x4 accg[4][2], accu[4][2];
#pragma unroll
    for (int i = 0; i < 4; i++)
#pragma unroll
        for (int j = 0; j < 2; j++) {
            accg[i][j] = (f32x4){0.f, 0.f, 0.f, 0.f};
            accu[i][j] = (f32x4){0.f, 0.f, 0.f, 0.f};
        }

    int arow[4], brow[2];
#pragma unroll
    for (int fm = 0; fm < 4; fm++) arow[fm] = (wm * 64 + fm * 16 + lrow) * 64;
#pragma unroll
    for (int fn = 0; fn < 2; fn++) brow[fn] = (wn * 32 + fn * 16 + lrow) * 64;

    // prologue: stage k-tile 0 into buf 0 (8 VMEM ops/thread, left in flight)
#pragma unroll
    for (int j = 0; j < 4; j++) gl_lds16(srcA[j], As[0] + (wv * 256 + j * 64) * 8);
#pragma unroll
    for (int j = 0; j < 2; j++) {
        gl_lds16(srcG[j], Bg[0] + (wv * 128 + j * 64) * 8);
        gl_lds16(srcU[j], Bu[0] + (wv * 128 + j * 64) * 8);
    }
    MEMFENCE;

    int cur = 0;
    for (int k0 = 0; k0 < D_MODEL; k0 += 64, cur ^= 1) {
        bool more = (k0 + 64 < D_MODEL);
        if (more) {   // issue next k-tile into buf cur^1; stays in flight across barrier
            int nxt = cur ^ 1, kn = k0 + 64;
#pragma unroll
            for (int j = 0; j < 4; j++) gl_lds16(srcA[j] + kn, As[nxt] + (wv * 256 + j * 64) * 8);
#pragma unroll
            for (int j = 0; j < 2; j++) {
                gl_lds16(srcG[j] + kn, Bg[nxt] + (wv * 128 + j * 64) * 8);
                gl_lds16(srcU[j] + kn, Bu[nxt] + (wv * 128 + j * 64) * 8);
            }
            asm volatile("s_waitcnt vmcnt(8)" ::: "memory");   // tile t done; t+1 in flight
        } else {
            asm volatile("s_waitcnt vmcnt(0)" ::: "memory");
        }
        __builtin_amdgcn_s_barrier();
        MEMFENCE;

        const unsigned short* Ac = As[cur];
        const unsigned short* Gc = Bg[cur];
        const unsigned short* Uc = Bu[cur];
        __builtin_amdgcn_s_setprio(1);
#pragma unroll
        for (int ks = 0; ks < 2; ks++) {
            int co = 8 * ((4 * ks + kgrp) ^ swz);
            bf16x8 a[4], bg[2], bu[2];
#pragma unroll
            for (int fm = 0; fm < 4; fm++) a[fm] = *(const bf16x8*)&Ac[arow[fm] + co];
#pragma unroll
            for (int fn = 0; fn < 2; fn++) {
                bg[fn] = *(const bf16x8*)&Gc[brow[fn] + co];
                bu[fn] = *(const bf16x8*)&Bu[cur][brow[fn] + co];
            }
#pragma unroll
            for (int fm = 0; fm < 4; fm++)
#pragma unroll
                for (int fn = 0; fn < 2; fn++) {
                    accg[fm][fn] = __builtin_amdgcn_mfma_f32_16x16x32_bf16(a[fm], bg[fn], accg[fm][fn], 0, 0, 0);
                    accu[fm][fn] = __builtin_amdgcn_mfma_f32_16x16x32_bf16(a[fm], bu[fn], accu[fm][fn], 0, 0, 0);
                }
        }
        __builtin_amdgcn_s_setprio(0);
        MEMFENCE;
        asm volatile("s_waitcnt lgkmcnt(0)" ::: "memory");  // all ds_reads of buf[cur] retired
        __builtin_amdgcn_s_barrier();                        // buf[cur] safe to re-stage next iter
        MEMFENCE;
        (void)Uc;
    }

#pragma unroll
    for (int fm = 0; fm < 4; fm++)
#pragma unroll
        for (int fn = 0; fn < 2; fn++)
#pragma unroll
            for (int r = 0; r < 4; r++) {
                int m = wm * 64 + fm * 16 + kgrp * 4 + r;
                if (m < Mloc) {
                    int n = wn * 32 + fn * 16 + lrow;
                    float g = accg[fm][fn][r], u = accu[fm][fn][r];
                    float h = g / (1.f + __expf(-g)) * u;
                    H[(size_t)(row0 + m) * D_INNER + f0 + n] = f2b(h);
                }
            }
}

// ---------------- down GEMM + weighted scatter, counted-vmcnt pipeline ----------------
__global__ __launch_bounds__(256, 2) void moe_down(
    const unsigned short* __restrict__ H, const unsigned short* __restrict__ wdT,
    const int* __restrict__ meta, const int* __restrict__ tok_of_slot,
    const float* __restrict__ w_of_slot, float* __restrict__ out, int S2)
{
    __shared__ unsigned short As[2][BM * 64];
    __shared__ unsigned short Bs[2][BM * 64];
    __shared__ int toks[BM];
    __shared__ float wts[BM];

    int lin = blockIdx.x;
    int d0 = (lin & 7) * BM;
    int tix = lin >> 3;
    int packed = meta[16 + tix];
    if (packed < 0) return;
    int e = packed >> 16, row0 = packed & 0xffff;
    int Mloc = min(BM, meta[e + 1] - row0);

    int tid = threadIdx.x, wv = tid >> 6, lane = tid & 63;
    int l3 = lane >> 3, c3 = lane & 7;
    if (tid < BM) {
        bool v = tid < Mloc;
        toks[tid] = v ? tok_of_slot[row0 + tid] : 0;
        wts[tid] = v ? w_of_slot[row0 + tid] : 0.f;
    }

    const unsigned short* srcA[4]; const unsigned short* srcB[4];
#pragma unroll
    for (int j = 0; j < 4; j++) {
        int r = wv * 32 + j * 8 + l3;
        int slot = min(row0 + r, S2 - 1);
        srcA[j] = H + (size_t)slot * D_INNER + 8 * (c3 ^ (r & 7));
        srcB[j] = wdT + (size_t)e * D_INNER * D_MODEL + (size_t)(d0 + r) * D_INNER + 8 * (c3 ^ (r & 7));
    }

    int wm = wv >> 1, wn = wv & 1;
    int lrow = lane & 15, kgrp = lane >> 4;
    int swz = lrow & 7;

    f32x4 acc[4][4];
#pragma unroll
    for (int i = 0; i < 4; i++)
#pragma unroll
        for (int j = 0; j < 4; j++) acc[i][j] = (f32x4){0.f, 0.f, 0.f, 0.f};

    int arow[4], brow[4];
#pragma unroll
    for (int fm = 0; fm < 4; fm++) arow[fm] = (wm * 64 + fm * 16 + lrow) * 64;
#pragma unroll
    for (int fn = 0; fn < 4; fn++) brow[fn] = (wn * 64 + fn * 16 + lrow) * 64;

#pragma unroll
    for (int j = 0; j < 4; j++) {
        gl_lds16(srcA[j], As[0] + (wv * 256 + j * 64) * 8);
        gl_lds16(srcB[j], Bs[0] + (wv * 256 + j * 64) * 8);
    }
    MEMFENCE;

    int cur = 0;
    for (int k0 = 0; k0 < D_INNER; k0 += 64, cur ^= 1) {
        bool more = (k0 + 64 < D_INNER);
        if (more) {
            int nxt = cur ^ 1, kn = k0 + 64;
#pragma unroll
            for (int j = 0; j < 4; j++) {
                gl_lds16(srcA[j] + kn, As[nxt] + (wv * 256 + j * 64) * 8);
                gl_lds16(srcB[j] + kn, Bs[nxt] + (wv * 256 + j * 64) * 8);
            }
            asm volatile("s_waitcnt vmcnt(8)" ::: "memory");
        } else {
            asm volatile("s_waitcnt vmcnt(0)" ::: "memory");
        }
        __builtin_amdgcn_s_barrier();
        MEMFENCE;

        const unsigned short* Ac = As[cur];
        const unsigned short* Bc = Bs[cur];
        __builtin_amdgcn_s_setprio(1);
#pragma unroll
        for (int ks = 0; ks < 2; ks++) {
            int co = 8 * ((4 * ks + kgrp) ^ swz);
            bf16x8 a[4], b[4];
#pragma unroll
            for (int fm = 0; fm < 4; fm++) a[fm] = *(const bf16x8*)&Ac[arow[fm] + co];
#pragma unroll
            for (int fn = 0; fn < 4; fn++) b[fn] = *(const bf16x8*)&Bc[brow[fn] + co];
#pragma unroll
            for (int fm = 0; fm < 4; fm++)
#pragma unroll
                for (int fn = 0; fn < 4; fn++)
                    acc[fm][fn] = __builtin_amdgcn_mfma_f32_16x16x32_bf16(a[fm], b[fn], acc[fm][fn], 0, 0, 0);
        }
        __builtin_amdgcn_s_setprio(0);
        MEMFENCE;
        asm volatile("s_waitcnt lgkmcnt(0)" ::: "memory");
        __builtin_amdgcn_s_barrier();
        MEMFENCE;
    }

#pragma unroll
    for (int fm = 0; fm < 4; fm++)
#pragma unroll
        for (int fn = 0; fn < 4; fn++)
#pragma unroll
            for (int r = 0; r < 4; r++) {
                int m = wm * 64 + fm * 16 + kgrp * 4 + r;
                if (m < Mloc) {
                    int n = wn * 64 + fn * 16 + lrow;
                    atomicAdd(&out[(size_t)toks[m] * D_MODEL + d0 + n], wts[m] * acc[fm][fn][r]);
                }
            }
}

extern "C" void kernel_launch(void* const* d_in, const int* in_sizes, int n_in,
                              void* d_out, int out_size, void* d_ws, size_t ws_size,
                              hipStream_t stream) {
    const float* x  = (const float*)d_in[0];
    const float* rw = (const float*)d_in[1];
    const float* rb = (const float*)d_in[2];
    const float* gw = (const float*)d_in[3];
    const float* uw = (const float*)d_in[4];
    const float* dw = (const float*)d_in[5];
    float* out = (float*)d_out;

    int T = in_sizes[0] / D_MODEL;   // 4096
    int S2 = 2 * T;                   // 8192 slots

    char* ws = (char*)d_ws;
    size_t cur = 0;
    auto take = [&](size_t bytes) { char* p = ws + cur; cur = (cur + bytes + 255) & ~(size_t)255; return p; };
    int*   top_i = (int*)take((size_t)S2 * 4);
    float* top_w = (float*)take((size_t)S2 * 4);
    int*   meta  = (int*)take(1024);
    int*   tos   = (int*)take((size_t)S2 * 4);
    float* wos   = (float*)take((size_t)S2 * 4);
    unsigned short* xb  = (unsigned short*)take((size_t)T * D_MODEL * 2);
    unsigned short* wgT = (unsigned short*)take((size_t)NEXP * D_MODEL * D_INNER * 2);
    unsigned short* wuT = (unsigned short*)take((size_t)NEXP * D_MODEL * D_INNER * 2);
    unsigned short* wdT = (unsigned short*)take((size_t)NEXP * D_MODEL * D_INNER * 2);
    unsigned short* H   = (unsigned short*)take((size_t)S2 * D_INNER * 2);

    hipMemsetAsync(d_out, 0, (size_t)out_size * sizeof(float), stream);

    int n8 = T * D_MODEL / 8;
    cast_x_kernel<<<(n8 + 255) / 256, 256, 0, stream>>>(x, xb, n8);
    tcast_kernel<<<dim3(D_INNER / 64, D_MODEL / 64, NEXP), 256, 0, stream>>>(gw, wgT, D_MODEL, D_INNER);
    tcast_kernel<<<dim3(D_INNER / 64, D_MODEL / 64, NEXP), 256, 0, stream>>>(uw, wuT, D_MODEL, D_INNER);
    tcast_kernel<<<dim3(D_MODEL / 64, D_INNER / 64, NEXP), 256, 0, stream>>>(dw, wdT, D_INNER, D_MODEL);

    router_kernel<<<T, 64, 0, stream>>>(x, rw, rb, top_i, top_w, T);
    bucket_kernel<<<1, 256, 0, stream>>>(top_i, top_w, meta, tos, wos, T);

    moe_gate_up<<<MAXT * 32, 256, 0, stream>>>(xb, wgT, wuT, meta, tos, H);
    moe_down<<<MAXT * 8, 256, 0, stream>>>(H, wdT, meta, tos, wos, out, S2);
}

// Round 5
// 273.106 us; speedup vs baseline: 3.6511x; 1.0758x over previous
//
#include <hip/hip_runtime.h>
#include <hip/hip_bf16.h>
#include <stdint.h>

#define D_MODEL 1024
#define D_INNER 2048
#define NEXP 8
#define TOPK 2
#define BM 128
#define MAXT 72   // max M-tiles: floor(8192/128) + (NEXP-1) = 71, padded

typedef float f32x4 __attribute__((ext_vector_type(4)));
typedef short bf16x8 __attribute__((ext_vector_type(8)));

#define MEMFENCE asm volatile("" ::: "memory")

__device__ __forceinline__ unsigned short f2b(float f) {
    union { float f; uint32_t u; } v; v.f = f;
    uint32_t u = v.u;
    return (unsigned short)((u + 0x7fffu + ((u >> 16) & 1u)) >> 16);
}

__device__ __forceinline__ void gl_lds16(const void* g, void* l) {
    __builtin_amdgcn_global_load_lds((const __attribute__((address_space(1))) void*)g,
                                     (__attribute__((address_space(3))) void*)l, 16, 0, 0);
}

// ---------------- cast x: fp32 -> bf16 ----------------
__global__ __launch_bounds__(256) void cast_x_kernel(
    const float* __restrict__ in, unsigned short* __restrict__ out, int n8)
{
    int i = blockIdx.x * 256 + threadIdx.x;
    if (i >= n8) return;
    const float4* p = (const float4*)(in + (size_t)i * 8);
    float4 a = p[0], b = p[1];
    unsigned short o[8] = {f2b(a.x), f2b(a.y), f2b(a.z), f2b(a.w),
                           f2b(b.x), f2b(b.y), f2b(b.z), f2b(b.w)};
    *(uint4*)(out + (size_t)i * 8) = *(uint4*)o;
}

// ------------- cast+transpose weights: [E][K][N] fp32 -> [E][N][K] bf16 -------------
__global__ __launch_bounds__(256) void tcast_kernel(
    const float* __restrict__ in, unsigned short* __restrict__ out, int K, int N)
{
    __shared__ unsigned short S[64][68];
    int e = blockIdx.z;
    int n0 = blockIdx.x * 64, k0 = blockIdx.y * 64;
    const float* ib = in + (size_t)e * K * N;
    unsigned short* ob = out + (size_t)e * N * K;
    int tid = threadIdx.x;
    int kk = tid >> 4, nn4 = (tid & 15) * 4;
#pragma unroll
    for (int j = 0; j < 4; j++) {
        int k = kk + 16 * j;
        float4 v = *(const float4*)&ib[(size_t)(k0 + k) * N + n0 + nn4];
        ushort4 s; s.x = f2b(v.x); s.y = f2b(v.y); s.z = f2b(v.z); s.w = f2b(v.w);
        *(ushort4*)&S[k][nn4] = s;
    }
    __syncthreads();
    int nn = tid >> 4, kk4 = (tid & 15) * 4;
#pragma unroll
    for (int j = 0; j < 4; j++) {
        int n = nn + 16 * j;
        ushort4 s;
        s.x = S[kk4 + 0][n]; s.y = S[kk4 + 1][n];
        s.z = S[kk4 + 2][n]; s.w = S[kk4 + 3][n];
        *(ushort4*)&ob[(size_t)(n0 + n) * K + k0 + kk4] = s;
    }
}

// ---------------- router: 1 wave per token ----------------
__global__ __launch_bounds__(64) void router_kernel(
    const float* __restrict__ x, const float* __restrict__ rw,
    const float* __restrict__ rb, int* __restrict__ top_i,
    float* __restrict__ top_w, int T)
{
    int t = blockIdx.x;
    if (t >= T) return;
    int l = threadIdx.x;
    float xv[16];
#pragma unroll
    for (int i = 0; i < 16; i++) xv[i] = x[(size_t)t * D_MODEL + l + 64 * i];
    float logit[NEXP];
#pragma unroll
    for (int e = 0; e < NEXP; e++) {
        float acc = 0.f;
#pragma unroll
        for (int i = 0; i < 16; i++) acc += xv[i] * rw[e * D_MODEL + l + 64 * i];
#pragma unroll
        for (int s = 32; s > 0; s >>= 1) acc += __shfl_xor(acc, s, 64);
        logit[e] = acc + rb[e];
    }
    if (l == 0) {
        int i0 = 0; float m0 = logit[0];
#pragma unroll
        for (int e = 1; e < NEXP; e++) if (logit[e] > m0) { m0 = logit[e]; i0 = e; }
        int i1 = -1; float m1 = -3.0e38f;
#pragma unroll
        for (int e = 0; e < NEXP; e++) {
            if (e == i0) continue;
            if (logit[e] > m1) { m1 = logit[e]; i1 = e; }
        }
        float w0 = 1.f / (1.f + expf(m1 - m0));
        top_i[t * 2 + 0] = i0; top_i[t * 2 + 1] = i1;
        top_w[t * 2 + 0] = w0; top_w[t * 2 + 1] = 1.f - w0;
    }
}

// ---------------- bucket build + compact tile worklist: 1 block ----------------
__global__ __launch_bounds__(256) void bucket_kernel(
    const int* __restrict__ top_i, const float* __restrict__ top_w,
    int* __restrict__ meta, int* __restrict__ tok_of_slot,
    float* __restrict__ w_of_slot, int T)
{
    __shared__ int cnt[256][NEXP];
    __shared__ int pre[256][NEXP];
    __shared__ int tot[NEXP];
    __shared__ int off[NEXP + 1];
    int tid = threadIdx.x;
    int per = (T + 255) / 256;
    int t0 = tid * per;
    for (int e = 0; e < NEXP; e++) cnt[tid][e] = 0;
    for (int t = t0; t < t0 + per && t < T; t++)
        for (int k = 0; k < TOPK; k++) cnt[tid][top_i[t * 2 + k]]++;
    __syncthreads();
    if (tid < NEXP) {
        int run = 0;
        for (int i = 0; i < 256; i++) { pre[i][tid] = run; run += cnt[i][tid]; }
        tot[tid] = run;
    }
    __syncthreads();
    if (tid == 0) {
        off[0] = 0;
        for (int e = 0; e < NEXP; e++) off[e + 1] = off[e] + tot[e];
        for (int e = 0; e <= NEXP; e++) meta[e] = off[e];
        int nt = 0;
        for (int e = 0; e < NEXP; e++)
            for (int r = off[e]; r < off[e + 1]; r += BM)
                meta[16 + nt++] = (e << 16) | r;
        for (; nt < MAXT; nt++) meta[16 + nt] = -1;
    }
    __syncthreads();
    int lc[NEXP];
#pragma unroll
    for (int e = 0; e < NEXP; e++) lc[e] = 0;
    for (int t = t0; t < t0 + per && t < T; t++) {
        for (int k = 0; k < TOPK; k++) {
            int e = top_i[t * 2 + k];
            int slot = off[e] + pre[tid][e] + lc[e]++;
            tok_of_slot[slot] = t;
            w_of_slot[slot] = top_w[t * 2 + k];
        }
    }
}

// ---------------- gate+up GEMM + swiglu -> H ----------------
// Tile M=128 x F=128 (g and u), K_STEP=32, 3 LDS buffers (72KB dynamic), 2-deep
// prefetch, counted vmcnt. Per wave: 64x64 of g AND u (A-frags shared) -> AI 42.7.
__global__ __launch_bounds__(256, 2) void moe_gate_up(
    const unsigned short* __restrict__ xb, const unsigned short* __restrict__ wgT,
    const unsigned short* __restrict__ wuT, const int* __restrict__ meta,
    const int* __restrict__ tok_of_slot, unsigned short* __restrict__ H)
{
    extern __shared__ __align__(16) unsigned short lds[];   // 3 * 12288 ushorts

    int lin = blockIdx.x;
    int strip = (lin & 7) * 2 + ((lin >> 3) & 1);   // lin%8 = XCD -> strip pair
    int tix = lin >> 4;
    int packed = meta[16 + tix];
    if (packed < 0) return;
    int e = packed >> 16, row0 = packed & 0xffff;
    int Mloc = min(BM, meta[e + 1] - row0);
    int f0 = strip * 128;

    int tid = threadIdx.x, wv = tid >> 6, lane = tid & 63;

    // staging source pointers (2 rounds each for A/Bg/Bu)
    const unsigned short* srcA[2];
    const unsigned short* srcG[2];
    const unsigned short* srcU[2];
#pragma unroll
    for (int j = 0; j < 2; j++) {
        int row = j * 64 + (tid >> 2);
        int p = tid & 3;
        int koffA = 8 * (p ^ ((row >> 1) & 3));
        int slot = row0 + ((row < Mloc) ? row : 0);
        srcA[j] = xb + (size_t)tok_of_slot[slot] * D_MODEL + koffA;
        size_t wb = (size_t)e * D_MODEL * D_INNER + (size_t)(f0 + row) * D_MODEL + koffA;
        srcG[j] = wgT + wb;
        srcU[j] = wuT + wb;
    }

    int wm = wv >> 1, wn = wv & 1;
    int lrow = lane & 15, kgrp = lane >> 4;
    int co = 8 * (kgrp ^ ((lrow >> 1) & 3));

    int arow[4], brow[4];
#pragma unroll
    for (int fm = 0; fm < 4; fm++) arow[fm] = (wm * 64 + fm * 16 + lrow) * 32;
#pragma unroll
    for (int fn = 0; fn < 4; fn++) brow[fn] = (wn * 64 + fn * 16 + lrow) * 32;

    f32x4 accg[4][4], accu[4][4];
#pragma unroll
    for (int i = 0; i < 4; i++)
#pragma unroll
        for (int j = 0; j < 4; j++) {
            accg[i][j] = (f32x4){0.f, 0.f, 0.f, 0.f};
            accu[i][j] = (f32x4){0.f, 0.f, 0.f, 0.f};
        }

    auto stage = [&](int u) {
        int kk = u * 32;
        unsigned short* base = lds + (u % 3) * 12288;
#pragma unroll
        for (int j = 0; j < 2; j++) {
            int d = (j * 256 + wv * 64) * 8;
            gl_lds16(srcA[j] + kk, base + d);
            gl_lds16(srcG[j] + kk, base + 4096 + d);
            gl_lds16(srcU[j] + kk, base + 8192 + d);
        }
    };

    const int NT = D_MODEL / 32;   // 32
    stage(0); stage(1);
    MEMFENCE;

    for (int t = 0; t < NT; ++t) {
        if (t + 2 < NT) stage(t + 2);
        int ahead = NT - 1 - t;
        if (ahead >= 2)      asm volatile("s_waitcnt vmcnt(12)" ::: "memory");
        else if (ahead == 1) asm volatile("s_waitcnt vmcnt(6)"  ::: "memory");
        else                 asm volatile("s_waitcnt vmcnt(0)"  ::: "memory");
        __builtin_amdgcn_s_barrier();
        MEMFENCE;

        const unsigned short* base = lds + (t % 3) * 12288;
        bf16x8 a[4], bg[4], bu[4];
#pragma unroll
        for (int fm = 0; fm < 4; fm++) a[fm] = *(const bf16x8*)(base + arow[fm] + co);
#pragma unroll
        for (int fn = 0; fn < 4; fn++) {
            bg[fn] = *(const bf16x8*)(base + 4096 + brow[fn] + co);
            bu[fn] = *(const bf16x8*)(base + 8192 + brow[fn] + co);
        }
        __builtin_amdgcn_s_setprio(1);
#pragma unroll
        for (int fm = 0; fm < 4; fm++)
#pragma unroll
            for (int fn = 0; fn < 4; fn++) {
                accg[fm][fn] = __builtin_amdgcn_mfma_f32_16x16x32_bf16(a[fm], bg[fn], accg[fm][fn], 0, 0, 0);
                accu[fm][fn] = __builtin_amdgcn_mfma_f32_16x16x32_bf16(a[fm], bu[fn], accu[fm][fn], 0, 0, 0);
            }
        __builtin_amdgcn_s_setprio(0);
        MEMFENCE;
        asm volatile("s_waitcnt lgkmcnt(0)" ::: "memory");
        __builtin_amdgcn_s_barrier();
        MEMFENCE;
    }

#pragma unroll
    for (int fm = 0; fm < 4; fm++)
#pragma unroll
        for (int fn = 0; fn < 4; fn++)
#pragma unroll
            for (int r = 0; r < 4; r++) {
                int m = wm * 64 + fm * 16 + kgrp * 4 + r;
                if (m < Mloc) {
                    int n = wn * 64 + fn * 16 + lrow;
                    float g = accg[fm][fn][r], u = accu[fm][fn][r];
                    float h = g / (1.f + __expf(-g)) * u;
                    H[(size_t)(row0 + m) * D_INNER + f0 + n] = f2b(h);
                }
            }
}

// ---------------- down GEMM + weighted scatter ----------------
// Tile M=128 x N=128, K_STEP=32, 3 LDS buffers (48KB static), 2-deep prefetch.
__global__ __launch_bounds__(256, 2) void moe_down(
    const unsigned short* __restrict__ H, const unsigned short* __restrict__ wdT,
    const int* __restrict__ meta, const int* __restrict__ tok_of_slot,
    const float* __restrict__ w_of_slot, float* __restrict__ out, int S2)
{
    __shared__ unsigned short lds[3 * 8192];
    __shared__ int toks[BM];
    __shared__ float wts[BM];

    int lin = blockIdx.x;
    int d0 = (lin & 7) * 128;
    int tix = lin >> 3;
    int packed = meta[16 + tix];
    if (packed < 0) return;
    int e = packed >> 16, row0 = packed & 0xffff;
    int Mloc = min(BM, meta[e + 1] - row0);

    int tid = threadIdx.x, wv = tid >> 6, lane = tid & 63;
    if (tid < BM) {
        bool v = tid < Mloc;
        toks[tid] = v ? tok_of_slot[row0 + tid] : 0;
        wts[tid] = v ? w_of_slot[row0 + tid] : 0.f;
    }

    const unsigned short* srcA[2];
    const unsigned short* srcB[2];
#pragma unroll
    for (int j = 0; j < 2; j++) {
        int row = j * 64 + (tid >> 2);
        int p = tid & 3;
        int koff = 8 * (p ^ ((row >> 1) & 3));
        int slot = min(row0 + row, S2 - 1);
        srcA[j] = H + (size_t)slot * D_INNER + koff;
        srcB[j] = wdT + (size_t)e * D_INNER * D_MODEL + (size_t)(d0 + row) * D_INNER + koff;
    }

    int wm = wv >> 1, wn = wv & 1;
    int lrow = lane & 15, kgrp = lane >> 4;
    int co = 8 * (kgrp ^ ((lrow >> 1) & 3));

    int arow[4], brow[4];
#pragma unroll
    for (int fm = 0; fm < 4; fm++) arow[fm] = (wm * 64 + fm * 16 + lrow) * 32;
#pragma unroll
    for (int fn = 0; fn < 4; fn++) brow[fn] = (wn * 64 + fn * 16 + lrow) * 32;

    f32x4 acc[4][4];
#pragma unroll
    for (int i = 0; i < 4; i++)
#pragma unroll
        for (int j = 0; j < 4; j++) acc[i][j] = (f32x4){0.f, 0.f, 0.f, 0.f};

    auto stage = [&](int u) {
        int kk = u * 32;
        unsigned short* base = lds + (u % 3) * 8192;
#pragma unroll
        for (int j = 0; j < 2; j++) {
            int d = (j * 256 + wv * 64) * 8;
            gl_lds16(srcA[j] + kk, base + d);
            gl_lds16(srcB[j] + kk, base + 4096 + d);
        }
    };

    const int NT = D_INNER / 32;   // 64
    stage(0); stage(1);
    MEMFENCE;

    for (int t = 0; t < NT; ++t) {
        if (t + 2 < NT) stage(t + 2);
        int ahead = NT - 1 - t;
        if (ahead >= 2)      asm volatile("s_waitcnt vmcnt(8)" ::: "memory");
        else if (ahead == 1) asm volatile("s_waitcnt vmcnt(4)" ::: "memory");
        else                 asm volatile("s_waitcnt vmcnt(0)" ::: "memory");
        __builtin_amdgcn_s_barrier();
        MEMFENCE;

        const unsigned short* base = lds + (t % 3) * 8192;
        bf16x8 a[4], b[4];
#pragma unroll
        for (int fm = 0; fm < 4; fm++) a[fm] = *(const bf16x8*)(base + arow[fm] + co);
#pragma unroll
        for (int fn = 0; fn < 4; fn++) b[fn] = *(const bf16x8*)(base + 4096 + brow[fn] + co);
        __builtin_amdgcn_s_setprio(1);
#pragma unroll
        for (int fm = 0; fm < 4; fm++)
#pragma unroll
            for (int fn = 0; fn < 4; fn++)
                acc[fm][fn] = __builtin_amdgcn_mfma_f32_16x16x32_bf16(a[fm], b[fn], acc[fm][fn], 0, 0, 0);
        __builtin_amdgcn_s_setprio(0);
        MEMFENCE;
        asm volatile("s_waitcnt lgkmcnt(0)" ::: "memory");
        __builtin_amdgcn_s_barrier();
        MEMFENCE;
    }

#pragma unroll
    for (int fm = 0; fm < 4; fm++)
#pragma unroll
        for (int fn = 0; fn < 4; fn++)
#pragma unroll
            for (int r = 0; r < 4; r++) {
                int m = wm * 64 + fm * 16 + kgrp * 4 + r;
                if (m < Mloc) {
                    int n = wn * 64 + fn * 16 + lrow;
                    atomicAdd(&out[(size_t)toks[m] * D_MODEL + d0 + n], wts[m] * acc[fm][fn][r]);
                }
            }
}

extern "C" void kernel_launch(void* const* d_in, const int* in_sizes, int n_in,
                              void* d_out, int out_size, void* d_ws, size_t ws_size,
                              hipStream_t stream) {
    const float* x  = (const float*)d_in[0];
    const float* rw = (const float*)d_in[1];
    const float* rb = (const float*)d_in[2];
    const float* gw = (const float*)d_in[3];
    const float* uw = (const float*)d_in[4];
    const float* dw = (const float*)d_in[5];
    float* out = (float*)d_out;

    int T = in_sizes[0] / D_MODEL;   // 4096
    int S2 = 2 * T;                   // 8192 slots

    char* ws = (char*)d_ws;
    size_t cur = 0;
    auto take = [&](size_t bytes) { char* p = ws + cur; cur = (cur + bytes + 255) & ~(size_t)255; return p; };
    int*   top_i = (int*)take((size_t)S2 * 4);
    float* top_w = (float*)take((size_t)S2 * 4);
    int*   meta  = (int*)take(1024);
    int*   tos   = (int*)take((size_t)S2 * 4);
    float* wos   = (float*)take((size_t)S2 * 4);
    unsigned short* xb  = (unsigned short*)take((size_t)T * D_MODEL * 2);
    unsigned short* wgT = (unsigned short*)take((size_t)NEXP * D_MODEL * D_INNER * 2);
    unsigned short* wuT = (unsigned short*)take((size_t)NEXP * D_MODEL * D_INNER * 2);
    unsigned short* wdT = (unsigned short*)take((size_t)NEXP * D_MODEL * D_INNER * 2);
    unsigned short* H   = (unsigned short*)take((size_t)S2 * D_INNER * 2);

    static const int GU_LDS = 3 * 12288 * 2;   // 73728 B dynamic LDS
    hipFuncSetAttribute((const void*)moe_gate_up,
                        hipFuncAttributeMaxDynamicSharedMemorySize, GU_LDS);

    hipMemsetAsync(d_out, 0, (size_t)out_size * sizeof(float), stream);

    int n8 = T * D_MODEL / 8;
    cast_x_kernel<<<(n8 + 255) / 256, 256, 0, stream>>>(x, xb, n8);
    tcast_kernel<<<dim3(D_INNER / 64, D_MODEL / 64, NEXP), 256, 0, stream>>>(gw, wgT, D_MODEL, D_INNER);
    tcast_kernel<<<dim3(D_INNER / 64, D_MODEL / 64, NEXP), 256, 0, stream>>>(uw, wuT, D_MODEL, D_INNER);
    tcast_kernel<<<dim3(D_MODEL / 64, D_INNER / 64, NEXP), 256, 0, stream>>>(dw, wdT, D_INNER, D_MODEL);

    router_kernel<<<T, 64, 0, stream>>>(x, rw, rb, top_i, top_w, T);
    bucket_kernel<<<1, 256, 0, stream>>>(top_i, top_w, meta, tos, wos, T);

    moe_gate_up<<<MAXT * 16, 256, GU_LDS, stream>>>(xb, wgT, wuT, meta, tos, H);
    moe_down<<<MAXT * 8, 256, 0, stream>>>(H, wdT, meta, tos, wos, out, S2);
}

// Round 6
// 266.662 us; speedup vs baseline: 3.7394x; 1.0242x over previous
//
#include <hip/hip_runtime.h>
#include <hip/hip_bf16.h>
#include <stdint.h>

#define D_MODEL 1024
#define D_INNER 2048
#define NEXP 8
#define TOPK 2
#define BM 128
#define MAXT 72   // max M-tiles: floor(8192/128) + (NEXP-1) = 71, padded

typedef float f32x4 __attribute__((ext_vector_type(4)));
typedef short bf16x8 __attribute__((ext_vector_type(8)));

#define MEMFENCE asm volatile("" ::: "memory")

__device__ __forceinline__ unsigned short f2b(float f) {
    union { float f; uint32_t u; } v; v.f = f;
    uint32_t u = v.u;
    return (unsigned short)((u + 0x7fffu + ((u >> 16) & 1u)) >> 16);
}

__device__ __forceinline__ void gl_lds16(const void* g, void* l) {
    __builtin_amdgcn_global_load_lds((const __attribute__((address_space(1))) void*)g,
                                     (__attribute__((address_space(3))) void*)l, 16, 0, 0);
}

// ---------------- cast x: fp32 -> bf16 ----------------
__global__ __launch_bounds__(256) void cast_x_kernel(
    const float* __restrict__ in, unsigned short* __restrict__ out, int n8)
{
    int i = blockIdx.x * 256 + threadIdx.x;
    if (i >= n8) return;
    const float4* p = (const float4*)(in + (size_t)i * 8);
    float4 a = p[0], b = p[1];
    unsigned short o[8] = {f2b(a.x), f2b(a.y), f2b(a.z), f2b(a.w),
                           f2b(b.x), f2b(b.y), f2b(b.z), f2b(b.w)};
    *(uint4*)(out + (size_t)i * 8) = *(uint4*)o;
}

// ------- cast+transpose all 3 weights: [E][K][N] fp32 -> [E][N][K] bf16, one launch -------
__global__ __launch_bounds__(256) void tcast3_kernel(
    const float* __restrict__ gw, const float* __restrict__ uw, const float* __restrict__ dw,
    unsigned short* __restrict__ gT, unsigned short* __restrict__ uT, unsigned short* __restrict__ dT)
{
    __shared__ unsigned short S[64][68];
    int which = blockIdx.z >> 3;
    int e = blockIdx.z & 7;
    const float* in; unsigned short* out; int K, N;
    if (which == 0)      { in = gw; out = gT; K = D_MODEL; N = D_INNER; }
    else if (which == 1) { in = uw; out = uT; K = D_MODEL; N = D_INNER; }
    else                 { in = dw; out = dT; K = D_INNER; N = D_MODEL; }
    int n0 = blockIdx.x * 64, k0 = blockIdx.y * 64;
    if (n0 >= N || k0 >= K) return;
    const float* ib = in + (size_t)e * K * N;
    unsigned short* ob = out + (size_t)e * N * K;
    int tid = threadIdx.x;
    int kk = tid >> 4, nn4 = (tid & 15) * 4;
#pragma unroll
    for (int j = 0; j < 4; j++) {
        int k = kk + 16 * j;
        float4 v = *(const float4*)&ib[(size_t)(k0 + k) * N + n0 + nn4];
        ushort4 s; s.x = f2b(v.x); s.y = f2b(v.y); s.z = f2b(v.z); s.w = f2b(v.w);
        *(ushort4*)&S[k][nn4] = s;
    }
    __syncthreads();
    int nn = tid >> 4, kk4 = (tid & 15) * 4;
#pragma unroll
    for (int j = 0; j < 4; j++) {
        int n = nn + 16 * j;
        ushort4 s;
        s.x = S[kk4 + 0][n]; s.y = S[kk4 + 1][n];
        s.z = S[kk4 + 2][n]; s.w = S[kk4 + 3][n];
        *(ushort4*)&ob[(size_t)(n0 + n) * K + k0 + kk4] = s;
    }
}

// ---------------- router: 1 wave per token ----------------
__global__ __launch_bounds__(64) void router_kernel(
    const float* __restrict__ x, const float* __restrict__ rw,
    const float* __restrict__ rb, int* __restrict__ top_i,
    float* __restrict__ top_w, int T)
{
    int t = blockIdx.x;
    if (t >= T) return;
    int l = threadIdx.x;
    float xv[16];
#pragma unroll
    for (int i = 0; i < 16; i++) xv[i] = x[(size_t)t * D_MODEL + l + 64 * i];
    float logit[NEXP];
#pragma unroll
    for (int e = 0; e < NEXP; e++) {
        float acc = 0.f;
#pragma unroll
        for (int i = 0; i < 16; i++) acc += xv[i] * rw[e * D_MODEL + l + 64 * i];
#pragma unroll
        for (int s = 32; s > 0; s >>= 1) acc += __shfl_xor(acc, s, 64);
        logit[e] = acc + rb[e];
    }
    if (l == 0) {
        int i0 = 0; float m0 = logit[0];
#pragma unroll
        for (int e = 1; e < NEXP; e++) if (logit[e] > m0) { m0 = logit[e]; i0 = e; }
        int i1 = -1; float m1 = -3.0e38f;
#pragma unroll
        for (int e = 0; e < NEXP; e++) {
            if (e == i0) continue;
            if (logit[e] > m1) { m1 = logit[e]; i1 = e; }
        }
        float w0 = 1.f / (1.f + expf(m1 - m0));
        top_i[t * 2 + 0] = i0; top_i[t * 2 + 1] = i1;
        top_w[t * 2 + 0] = w0; top_w[t * 2 + 1] = 1.f - w0;
    }
}

// ---------------- bucket build + compact tile worklist: 1 block ----------------
__global__ __launch_bounds__(256) void bucket_kernel(
    const int* __restrict__ top_i, const float* __restrict__ top_w,
    int* __restrict__ meta, int* __restrict__ tok_of_slot,
    float* __restrict__ w_of_slot, int T)
{
    __shared__ int cnt[256][NEXP];
    __shared__ int pre[256][NEXP];
    __shared__ int tot[NEXP];
    __shared__ int off[NEXP + 1];
    int tid = threadIdx.x;
    int per = (T + 255) / 256;
    int t0 = tid * per;
    for (int e = 0; e < NEXP; e++) cnt[tid][e] = 0;
    for (int t = t0; t < t0 + per && t < T; t++)
        for (int k = 0; k < TOPK; k++) cnt[tid][top_i[t * 2 + k]]++;
    __syncthreads();
    if (tid < NEXP) {
        int run = 0;
        for (int i = 0; i < 256; i++) { pre[i][tid] = run; run += cnt[i][tid]; }
        tot[tid] = run;
    }
    __syncthreads();
    if (tid == 0) {
        off[0] = 0;
        for (int e = 0; e < NEXP; e++) off[e + 1] = off[e] + tot[e];
        for (int e = 0; e <= NEXP; e++) meta[e] = off[e];
        int nt = 0;
        for (int e = 0; e < NEXP; e++)
            for (int r = off[e]; r < off[e + 1]; r += BM)
                meta[16 + nt++] = (e << 16) | r;
        for (; nt < MAXT; nt++) meta[16 + nt] = -1;
    }
    __syncthreads();
    int lc[NEXP];
#pragma unroll
    for (int e = 0; e < NEXP; e++) lc[e] = 0;
    for (int t = t0; t < t0 + per && t < T; t++) {
        for (int k = 0; k < TOPK; k++) {
            int e = top_i[t * 2 + k];
            int slot = off[e] + pre[tid][e] + lc[e]++;
            tok_of_slot[slot] = t;
            w_of_slot[slot] = top_w[t * 2 + k];
        }
    }
}

// ---------------- gate+up GEMM + swiglu -> H ----------------
// MFMA-first schedule: per iter {MFMA(frags t) -> stage(t+2) -> counted vmcnt ->
// ONE barrier -> ds_read frags(t+1)}. Frag reads get a full iteration to land.
// Safety: reads of buf b (iter t-1 issue) complete before each wave's MFMA(t)
// (data dep), which precedes barrier(t); restage of b = stage(t+2) is issued
// after barrier(t) by every wave. Other waves' stage(t+1) completion is
// published by their vmcnt before barrier(t).
__global__ __launch_bounds__(256, 2) void moe_gate_up(
    const unsigned short* __restrict__ xb, const unsigned short* __restrict__ wgT,
    const unsigned short* __restrict__ wuT, const int* __restrict__ meta,
    const int* __restrict__ tok_of_slot, unsigned short* __restrict__ H)
{
    extern __shared__ __align__(16) unsigned short lds[];   // 3 * 12288 ushorts

    int lin = blockIdx.x;
    int strip = (lin & 7) * 2 + ((lin >> 3) & 1);   // lin%8 = XCD -> strip pair
    int tix = lin >> 4;
    int packed = meta[16 + tix];
    if (packed < 0) return;
    int e = packed >> 16, row0 = packed & 0xffff;
    int Mloc = min(BM, meta[e + 1] - row0);
    int f0 = strip * 128;

    int tid = threadIdx.x, wv = tid >> 6, lane = tid & 63;

    const unsigned short* srcA[2];
    const unsigned short* srcG[2];
    const unsigned short* srcU[2];
#pragma unroll
    for (int j = 0; j < 2; j++) {
        int row = j * 64 + (tid >> 2);
        int p = tid & 3;
        int koffA = 8 * (p ^ ((row >> 1) & 3));
        int slot = row0 + ((row < Mloc) ? row : 0);
        srcA[j] = xb + (size_t)tok_of_slot[slot] * D_MODEL + koffA;
        size_t wb = (size_t)e * D_MODEL * D_INNER + (size_t)(f0 + row) * D_MODEL + koffA;
        srcG[j] = wgT + wb;
        srcU[j] = wuT + wb;
    }

    int wm = wv >> 1, wn = wv & 1;
    int lrow = lane & 15, kgrp = lane >> 4;
    int co = 8 * (kgrp ^ ((lrow >> 1) & 3));

    int arow[4], brow[4];
#pragma unroll
    for (int fm = 0; fm < 4; fm++) arow[fm] = (wm * 64 + fm * 16 + lrow) * 32;
#pragma unroll
    for (int fn = 0; fn < 4; fn++) brow[fn] = (wn * 64 + fn * 16 + lrow) * 32;

    f32x4 accg[4][4], accu[4][4];
#pragma unroll
    for (int i = 0; i < 4; i++)
#pragma unroll
        for (int j = 0; j < 4; j++) {
            accg[i][j] = (f32x4){0.f, 0.f, 0.f, 0.f};
            accu[i][j] = (f32x4){0.f, 0.f, 0.f, 0.f};
        }

    auto stage = [&](int u) {
        int kk = u * 32;
        unsigned short* base = lds + (u % 3) * 12288;
#pragma unroll
        for (int j = 0; j < 2; j++) {
            int d = (j * 256 + wv * 64) * 8;
            gl_lds16(srcA[j] + kk, base + d);
            gl_lds16(srcG[j] + kk, base + 4096 + d);
            gl_lds16(srcU[j] + kk, base + 8192 + d);
        }
    };

    bf16x8 a[4], bg[4], bu[4];
    auto load_frags = [&](int u) {
        const unsigned short* base = lds + (u % 3) * 12288;
#pragma unroll
        for (int fm = 0; fm < 4; fm++) a[fm] = *(const bf16x8*)(base + arow[fm] + co);
#pragma unroll
        for (int fn = 0; fn < 4; fn++) {
            bg[fn] = *(const bf16x8*)(base + 4096 + brow[fn] + co);
            bu[fn] = *(const bf16x8*)(base + 8192 + brow[fn] + co);
        }
    };

    const int NT = D_MODEL / 32;   // 32
    stage(0); stage(1);
    MEMFENCE;
    asm volatile("s_waitcnt vmcnt(6)" ::: "memory");   // tile 0 landed
    __builtin_amdgcn_s_barrier();
    MEMFENCE;
    load_frags(0);

    for (int t = 0; t < NT; ++t) {
        __builtin_amdgcn_sched_barrier(0);   // MFMA stays after prior barrier+reads
        __builtin_amdgcn_s_setprio(1);
#pragma unroll
        for (int fm = 0; fm < 4; fm++)
#pragma unroll
            for (int fn = 0; fn < 4; fn++) {
                accg[fm][fn] = __builtin_amdgcn_mfma_f32_16x16x32_bf16(a[fm], bg[fn], accg[fm][fn], 0, 0, 0);
                accu[fm][fn] = __builtin_amdgcn_mfma_f32_16x16x32_bf16(a[fm], bu[fn], accu[fm][fn], 0, 0, 0);
            }
        __builtin_amdgcn_s_setprio(0);
        __builtin_amdgcn_sched_barrier(0);   // nothing drifts into the MFMA cluster

        if (t + 2 < NT) {
            stage(t + 2);
            asm volatile("s_waitcnt vmcnt(6)" ::: "memory");   // tile t+1 landed (mine)
        } else if (t + 1 < NT) {
            asm volatile("s_waitcnt vmcnt(0)" ::: "memory");
        }
        __builtin_amdgcn_s_barrier();    // all waves: tile t+1 valid, buf(t+2)%3 free
        MEMFENCE;
        if (t + 1 < NT) load_frags(t + 1);   // async: consumed next iter
    }

#pragma unroll
    for (int fm = 0; fm < 4; fm++)
#pragma unroll
        for (int fn = 0; fn < 4; fn++)
#pragma unroll
            for (int r = 0; r < 4; r++) {
                int m = wm * 64 + fm * 16 + kgrp * 4 + r;
                if (m < Mloc) {
                    int n = wn * 64 + fn * 16 + lrow;
                    float g = accg[fm][fn][r], u = accu[fm][fn][r];
                    float h = g / (1.f + __expf(-g)) * u;
                    H[(size_t)(row0 + m) * D_INNER + f0 + n] = f2b(h);
                }
            }
}

// ---------------- down GEMM + weighted scatter, MFMA-first schedule ----------------
__global__ __launch_bounds__(256, 2) void moe_down(
    const unsigned short* __restrict__ H, const unsigned short* __restrict__ wdT,
    const int* __restrict__ meta, const int* __restrict__ tok_of_slot,
    const float* __restrict__ w_of_slot, float* __restrict__ out, int S2)
{
    __shared__ unsigned short lds[3 * 8192];
    __shared__ int toks[BM];
    __shared__ float wts[BM];

    int lin = blockIdx.x;
    int d0 = (lin & 7) * 128;
    int tix = lin >> 3;
    int packed = meta[16 + tix];
    if (packed < 0) return;
    int e = packed >> 16, row0 = packed & 0xffff;
    int Mloc = min(BM, meta[e + 1] - row0);

    int tid = threadIdx.x, wv = tid >> 6, lane = tid & 63;
    if (tid < BM) {
        bool v = tid < Mloc;
        toks[tid] = v ? tok_of_slot[row0 + tid] : 0;
        wts[tid] = v ? w_of_slot[row0 + tid] : 0.f;
    }

    const unsigned short* srcA[2];
    const unsigned short* srcB[2];
#pragma unroll
    for (int j = 0; j < 2; j++) {
        int row = j * 64 + (tid >> 2);
        int p = tid & 3;
        int koff = 8 * (p ^ ((row >> 1) & 3));
        int slot = min(row0 + row, S2 - 1);
        srcA[j] = H + (size_t)slot * D_INNER + koff;
        srcB[j] = wdT + (size_t)e * D_INNER * D_MODEL + (size_t)(d0 + row) * D_INNER + koff;
    }

    int wm = wv >> 1, wn = wv & 1;
    int lrow = lane & 15, kgrp = lane >> 4;
    int co = 8 * (kgrp ^ ((lrow >> 1) & 3));

    int arow[4], brow[4];
#pragma unroll
    for (int fm = 0; fm < 4; fm++) arow[fm] = (wm * 64 + fm * 16 + lrow) * 32;
#pragma unroll
    for (int fn = 0; fn < 4; fn++) brow[fn] = (wn * 64 + fn * 16 + lrow) * 32;

    f32x4 acc[4][4];
#pragma unroll
    for (int i = 0; i < 4; i++)
#pragma unroll
        for (int j = 0; j < 4; j++) acc[i][j] = (f32x4){0.f, 0.f, 0.f, 0.f};

    auto stage = [&](int u) {
        int kk = u * 32;
        unsigned short* base = lds + (u % 3) * 8192;
#pragma unroll
        for (int j = 0; j < 2; j++) {
            int d = (j * 256 + wv * 64) * 8;
            gl_lds16(srcA[j] + kk, base + d);
            gl_lds16(srcB[j] + kk, base + 4096 + d);
        }
    };

    bf16x8 a[4], b[4];
    auto load_frags = [&](int u) {
        const unsigned short* base = lds + (u % 3) * 8192;
#pragma unroll
        for (int fm = 0; fm < 4; fm++) a[fm] = *(const bf16x8*)(base + arow[fm] + co);
#pragma unroll
        for (int fn = 0; fn < 4; fn++) b[fn] = *(const bf16x8*)(base + 4096 + brow[fn] + co);
    };

    const int NT = D_INNER / 32;   // 64
    stage(0); stage(1);
    MEMFENCE;
    asm volatile("s_waitcnt vmcnt(4)" ::: "memory");
    __builtin_amdgcn_s_barrier();
    MEMFENCE;
    load_frags(0);

    for (int t = 0; t < NT; ++t) {
        __builtin_amdgcn_sched_barrier(0);
        __builtin_amdgcn_s_setprio(1);
#pragma unroll
        for (int fm = 0; fm < 4; fm++)
#pragma unroll
            for (int fn = 0; fn < 4; fn++)
                acc[fm][fn] = __builtin_amdgcn_mfma_f32_16x16x32_bf16(a[fm], b[fn], acc[fm][fn], 0, 0, 0);
        __builtin_amdgcn_s_setprio(0);
        __builtin_amdgcn_sched_barrier(0);

        if (t + 2 < NT) {
            stage(t + 2);
            asm volatile("s_waitcnt vmcnt(4)" ::: "memory");
        } else if (t + 1 < NT) {
            asm volatile("s_waitcnt vmcnt(0)" ::: "memory");
        }
        __builtin_amdgcn_s_barrier();
        MEMFENCE;
        if (t + 1 < NT) load_frags(t + 1);
    }

#pragma unroll
    for (int fm = 0; fm < 4; fm++)
#pragma unroll
        for (int fn = 0; fn < 4; fn++)
#pragma unroll
            for (int r = 0; r < 4; r++) {
                int m = wm * 64 + fm * 16 + kgrp * 4 + r;
                if (m < Mloc) {
                    int n = wn * 64 + fn * 16 + lrow;
                    atomicAdd(&out[(size_t)toks[m] * D_MODEL + d0 + n], wts[m] * acc[fm][fn][r]);
                }
            }
}

extern "C" void kernel_launch(void* const* d_in, const int* in_sizes, int n_in,
                              void* d_out, int out_size, void* d_ws, size_t ws_size,
                              hipStream_t stream) {
    const float* x  = (const float*)d_in[0];
    const float* rw = (const float*)d_in[1];
    const float* rb = (const float*)d_in[2];
    const float* gw = (const float*)d_in[3];
    const float* uw = (const float*)d_in[4];
    const float* dw = (const float*)d_in[5];
    float* out = (float*)d_out;

    int T = in_sizes[0] / D_MODEL;   // 4096
    int S2 = 2 * T;                   // 8192 slots

    char* ws = (char*)d_ws;
    size_t cur = 0;
    auto take = [&](size_t bytes) { char* p = ws + cur; cur = (cur + bytes + 255) & ~(size_t)255; return p; };
    int*   top_i = (int*)take((size_t)S2 * 4);
    float* top_w = (float*)take((size_t)S2 * 4);
    int*   meta  = (int*)take(1024);
    int*   tos   = (int*)take((size_t)S2 * 4);
    float* wos   = (float*)take((size_t)S2 * 4);
    unsigned short* xb  = (unsigned short*)take((size_t)T * D_MODEL * 2);
    unsigned short* wgT = (unsigned short*)take((size_t)NEXP * D_MODEL * D_INNER * 2);
    unsigned short* wuT = (unsigned short*)take((size_t)NEXP * D_MODEL * D_INNER * 2);
    unsigned short* wdT = (unsigned short*)take((size_t)NEXP * D_MODEL * D_INNER * 2);
    unsigned short* H   = (unsigned short*)take((size_t)S2 * D_INNER * 2);

    static const int GU_LDS = 3 * 12288 * 2;   // 73728 B dynamic LDS
    hipFuncSetAttribute((const void*)moe_gate_up,
                        hipFuncAttributeMaxDynamicSharedMemorySize, GU_LDS);

    hipMemsetAsync(d_out, 0, (size_t)out_size * sizeof(float), stream);

    int n8 = T * D_MODEL / 8;
    cast_x_kernel<<<(n8 + 255) / 256, 256, 0, stream>>>(x, xb, n8);
    tcast3_kernel<<<dim3(32, 32, 24), 256, 0, stream>>>(gw, uw, dw, wgT, wuT, wdT);

    router_kernel<<<T, 64, 0, stream>>>(x, rw, rb, top_i, top_w, T);
    bucket_kernel<<<1, 256, 0, stream>>>(top_i, top_w, meta, tos, wos, T);

    moe_gate_up<<<MAXT * 16, 256, GU_LDS, stream>>>(xb, wgT, wuT, meta, tos, H);
    moe_down<<<MAXT * 8, 256, 0, stream>>>(H, wdT, meta, tos, wos, out, S2);
}